// Round 18
// baseline (264.338 us; speedup 1.0000x reference)
//
#include <hip/hip_runtime.h>

#define NN 100000
#define NE 1250000
#define CIN 64
#define CH 64
#define CO 32
#define NG 128
#define NBLK ((NN + 255) / 256)    // 391 (node-grid for scans)
#define NBUCK 98                    // buckets of 1024 nodes: dst>>10 in [0,97]
#define BSHIFT 10
#define EPB 2048                    // edges per partition block
#define NBLKP ((NE + EPB - 1) / EPB) // 611
#define GGRID 2048                  // grid-stride GEMM grid

typedef unsigned short ushortT;

static __device__ inline ushortT f2bf(float v) {
  unsigned int u = __float_as_uint(v);
  u += 0x7FFFu + ((u >> 16) & 1u);   // round-to-nearest-even
  return (ushortT)(u >> 16);
}
static __device__ inline float bf2f(ushortT s) {
  return __uint_as_float(((unsigned int)s) << 16);
}

// ---------------- init: zero sums+bhist, per-graph counts (block 0) -----------
static __global__ void k_zero(float* __restrict__ sums, int* __restrict__ bhist,
                              const int* __restrict__ batch, float* __restrict__ counts) {
  int i = blockIdx.x * 256 + threadIdx.x;
  if (i < NG * CO) sums[i] = 0.0f;
  if (i < 128) bhist[i] = 0;
  if (blockIdx.x == 0 && threadIdx.x < NG) {
    int g = threadIdx.x;
    int lo = 0, hi = NN;
    while (lo < hi) { int m = (lo + hi) >> 1; if (batch[m] < g) lo = m + 1; else hi = m; }
    int lb = lo;
    lo = 0; hi = NN;
    while (lo < hi) { int m = (lo + hi) >> 1; if (batch[m] <= g) lo = m + 1; else hi = m; }
    counts[g] = (float)(lo - lb);
  }
}

// ---------------- bucket histogram (LDS-staged) ----------------
static __global__ __launch_bounds__(256) void k_bhist(const int* __restrict__ dst,
                                                      int* __restrict__ bhist) {
  __shared__ int lh[128];
  if (threadIdx.x < 128) lh[threadIdx.x] = 0;
  __syncthreads();
  int e0 = blockIdx.x * EPB, e1 = min(e0 + EPB, NE);
  for (int e = e0 + threadIdx.x; e < e1; e += 256)
    atomicAdd(&lh[dst[e] >> BSHIFT], 1);
  __syncthreads();
  if (threadIdx.x < 128) { int v = lh[threadIdx.x]; if (v) atomicAdd(&bhist[threadIdx.x], v); }
}

// ---------------- exclusive scan of bucket counts (1 block, 128 thr) ----------
static __global__ void k_bscan(const int* __restrict__ bhist, int* __restrict__ bbase,
                               int* __restrict__ bcursor) {
  __shared__ int tmp[128];
  int t = threadIdx.x;
  int v = bhist[t];
  tmp[t] = v;
  __syncthreads();
  for (int off = 1; off < 128; off <<= 1) {
    int a = (t >= off) ? tmp[t - off] : 0;
    __syncthreads();
    tmp[t] += a;
    __syncthreads();
  }
  int ex = tmp[t] - v;
  bbase[t] = ex;
  bcursor[t] = ex;
  if (t == 127) bbase[128] = tmp[127];  // == NE
}

// -- partition edges into bucket-grouped packed runs: pk = src | (d&1023)<<17 --
static __global__ __launch_bounds__(256) void k_part(const int* __restrict__ src,
                                                     const int* __restrict__ dst,
                                                     int* __restrict__ bcursor,
                                                     unsigned int* __restrict__ pairs) {
  __shared__ int lh[128], lbase[128], loff[128];
  if (threadIdx.x < 128) { lh[threadIdx.x] = 0; loff[threadIdx.x] = 0; }
  __syncthreads();
  int e0 = blockIdx.x * EPB, e1 = min(e0 + EPB, NE);
  for (int e = e0 + threadIdx.x; e < e1; e += 256)
    atomicAdd(&lh[dst[e] >> BSHIFT], 1);
  __syncthreads();
  if (threadIdx.x < 128) {
    int v = lh[threadIdx.x];
    lbase[threadIdx.x] = v ? atomicAdd(&bcursor[threadIdx.x], v) : 0;
  }
  __syncthreads();
  for (int e = e0 + threadIdx.x; e < e1; e += 256) {
    int d = dst[e], b = d >> BSHIFT;
    int o = atomicAdd(&loff[b], 1);
    pairs[lbase[b] + o] = (unsigned int)src[e] | ((unsigned int)(d & 1023) << 17);
  }
}

// ------- per-bucket degree via LDS histogram; coalesced degi/dinv writes ------
static __global__ __launch_bounds__(256) void k_bucket_a(const unsigned int* __restrict__ pairs,
                                                         const int* __restrict__ bbase,
                                                         int* __restrict__ degi,
                                                         float* __restrict__ dinv) {
  __shared__ int lh[1024];
  for (int t = threadIdx.x; t < 1024; t += 256) lh[t] = 0;
  __syncthreads();
  int b = blockIdx.x;
  int p0 = bbase[b], p1 = bbase[b + 1];
  for (int p = p0 + threadIdx.x; p < p1; p += 256)
    atomicAdd(&lh[pairs[p] >> 17], 1);
  __syncthreads();
  int nb = b << BSHIFT;
  for (int t = threadIdx.x; t < 1024; t += 256) {
    int node = nb + t;
    if (node < NN) { int dg = lh[t]; degi[node] = dg; dinv[node] = rsqrtf((float)dg + 1.0f); }
  }
}

// ---------------- prefix scan of degrees -> CSR row starts ----------------
static __global__ void k_scanA(const int* __restrict__ degi, int* __restrict__ bsum) {
  __shared__ int tmp[256];
  int i = blockIdx.x * 256 + threadIdx.x;
  int v = (i < NN) ? degi[i] : 0;
  tmp[threadIdx.x] = v;
  __syncthreads();
  for (int off = 128; off > 0; off >>= 1) {
    if (threadIdx.x < off) tmp[threadIdx.x] += tmp[threadIdx.x + off];
    __syncthreads();
  }
  if (threadIdx.x == 0) bsum[blockIdx.x] = tmp[0];
}

static __global__ void k_scanB(const int* __restrict__ bsum, int* __restrict__ bbase2) {
  __shared__ int tmp[512];
  int t = threadIdx.x;
  int v = (t < NBLK) ? bsum[t] : 0;
  tmp[t] = v;
  __syncthreads();
  for (int off = 1; off < 512; off <<= 1) {
    int add = (t >= off) ? tmp[t - off] : 0;
    __syncthreads();
    tmp[t] += add;
    __syncthreads();
  }
  if (t < NBLK) bbase2[t] = tmp[t] - v;  // exclusive
}

static __global__ void k_scanC(const int* __restrict__ degi, const int* __restrict__ bbase2,
                               int* __restrict__ rowstart) {
  __shared__ int tmp[256];
  int i = blockIdx.x * 256 + threadIdx.x;
  int v = (i < NN) ? degi[i] : 0;
  tmp[threadIdx.x] = v;
  __syncthreads();
  for (int off = 1; off < 256; off <<= 1) {
    int add = (threadIdx.x >= off) ? tmp[threadIdx.x - off] : 0;
    __syncthreads();
    tmp[threadIdx.x] += add;
    __syncthreads();
  }
  if (i < NN) rowstart[i] = bbase2[blockIdx.x] + tmp[threadIdx.x] - v;  // exclusive
}

// ------- per-bucket CSR scatter with LDS cursors (localized writes) -----------
static __global__ __launch_bounds__(256) void k_bucket_b(const unsigned int* __restrict__ pairs,
                                                         const int* __restrict__ bbase,
                                                         const int* __restrict__ rowstart,
                                                         int* __restrict__ csr_src) {
  __shared__ int cur[1024];
  int b = blockIdx.x, nb = b << BSHIFT;
  for (int t = threadIdx.x; t < 1024; t += 256) {
    int node = nb + t;
    cur[t] = (node < NN) ? rowstart[node] : 0;
  }
  __syncthreads();
  int p0 = bbase[b], p1 = bbase[b + 1];
  for (int p = p0 + threadIdx.x; p < p1; p += 256) {
    unsigned int pk = pairs[p];
    int pos = atomicAdd(&cur[pk >> 17], 1);
    csr_src[pos] = (int)(pk & 0x1FFFFu);
  }
}

// -- GEMM 1: h' = bf16(dinv*(x @ W1)); W col in regs; x row via SCALAR loads ---
static __global__ __launch_bounds__(256) void k_gemm1(const float* __restrict__ x,
                                                      const float* __restrict__ W,
                                                      const float* __restrict__ dinv,
                                                      ushortT* __restrict__ h) {
  int wave = threadIdx.x >> 6;
  int lane = threadIdx.x & 63;
  float wr[CIN];
#pragma unroll
  for (int k = 0; k < CIN; ++k) wr[k] = W[k * CH + lane];  // coalesced, once
  for (int row0 = blockIdx.x * 4 + wave; row0 < NN; row0 += GGRID * 4) {
    int row = __builtin_amdgcn_readfirstlane(row0);
    const float4* xr = reinterpret_cast<const float4*>(x + (size_t)row * CIN);
    float dv = dinv[row];  // uniform -> scalar load
    float a0 = 0.f, a1 = 0.f, a2 = 0.f, a3 = 0.f;
#pragma unroll
    for (int k4 = 0; k4 < CIN / 4; k4 += 4) {
      float4 v0 = xr[k4 + 0];
      float4 v1 = xr[k4 + 1];
      float4 v2 = xr[k4 + 2];
      float4 v3 = xr[k4 + 3];
      a0 += v0.x * wr[4 * k4 + 0] + v0.y * wr[4 * k4 + 1] + v0.z * wr[4 * k4 + 2] + v0.w * wr[4 * k4 + 3];
      a1 += v1.x * wr[4 * k4 + 4] + v1.y * wr[4 * k4 + 5] + v1.z * wr[4 * k4 + 6] + v1.w * wr[4 * k4 + 7];
      a2 += v2.x * wr[4 * k4 + 8] + v2.y * wr[4 * k4 + 9] + v2.z * wr[4 * k4 + 10] + v2.w * wr[4 * k4 + 11];
      a3 += v3.x * wr[4 * k4 + 12] + v3.y * wr[4 * k4 + 13] + v3.z * wr[4 * k4 + 14] + v3.w * wr[4 * k4 + 15];
    }
    h[(size_t)row * CH + lane] = f2bf(((a0 + a1) + (a2 + a3)) * dv);
  }
}

// -- layer-1 agg, 4-rows-per-gather: lane group g (16 lanes) handles k%4==g ----
// out = relu(dinv*(self + sum_nbrs) + b1), written by group 0 as float4
static __global__ __launch_bounds__(256) void k_agg64(const ushortT* __restrict__ h,
                                                      const float* __restrict__ dinv,
                                                      const int* __restrict__ rowstart,
                                                      const int* __restrict__ degi,
                                                      const int* __restrict__ csr_src,
                                                      const float* __restrict__ b1,
                                                      float* __restrict__ agg) {
  int wave = threadIdx.x >> 6, lane = threadIdx.x & 63;
  int g = lane >> 4;          // neighbor sub-slot 0..3
  int j = lane & 15;          // ushort4 index within row (4 channels)
  int i = blockIdx.x * 4 + wave;  // grid exact: 25000*4
  const ushort4* hp = reinterpret_cast<const ushort4*>(h);
  int s0 = rowstart[i], n = degi[i];
  float ax = 0.f, ay = 0.f, az = 0.f, aw = 0.f;
  int niter = (n + 3) >> 2;
  for (int it = 0; it < niter; ++it) {
    int kk = it * 4 + g;
    int kidx = kk < n ? kk : n - 1;
    int s = csr_src[s0 + kidx];
    float m = kk < n ? 1.0f : 0.0f;
    ushort4 hv = hp[(size_t)s * 16 + j];
    ax += m * bf2f(hv.x);
    ay += m * bf2f(hv.y);
    az += m * bf2f(hv.z);
    aw += m * bf2f(hv.w);
  }
  // reduce across the 4 lane groups (lanes with same j)
  ax += __shfl_xor(ax, 16); ay += __shfl_xor(ay, 16); az += __shfl_xor(az, 16); aw += __shfl_xor(aw, 16);
  ax += __shfl_xor(ax, 32); ay += __shfl_xor(ay, 32); az += __shfl_xor(az, 32); aw += __shfl_xor(aw, 32);
  if (g == 0) {
    ushort4 sv = hp[(size_t)i * 16 + j];      // self-loop row
    float di = dinv[i];
    const float4* b1v = reinterpret_cast<const float4*>(b1);
    float4 bias = b1v[j];
    float4 o;
    o.x = (ax + bf2f(sv.x)) * di + bias.x; o.x = o.x > 0.f ? o.x : 0.f;
    o.y = (ay + bf2f(sv.y)) * di + bias.y; o.y = o.y > 0.f ? o.y : 0.f;
    o.z = (az + bf2f(sv.z)) * di + bias.z; o.z = o.z > 0.f ? o.z : 0.f;
    o.w = (aw + bf2f(sv.w)) * di + bias.w; o.w = o.w > 0.f ? o.w : 0.f;
    *reinterpret_cast<float4*>(agg + (size_t)i * CH + j * 4) = o;
  }
}

// -- GEMM 2: h2' = bf16(dinv*(aggRelu @ W2)); W2 column in 64 registers --------
static __global__ __launch_bounds__(256) void k_gemm2(const float* __restrict__ agg1,
                                                      const float* __restrict__ W,
                                                      const float* __restrict__ dinv,
                                                      ushortT* __restrict__ h2) {
  int half = threadIdx.x >> 5;
  int j = threadIdx.x & 31;
  float wr[CH];
#pragma unroll
  for (int k = 0; k < CH; ++k) wr[k] = W[k * CO + j];  // coalesced, once
  for (int row = blockIdx.x * 8 + half; row < NN; row += GGRID * 8) {
    const float4* ar = reinterpret_cast<const float4*>(agg1 + (size_t)row * CH);
    float acc = 0.0f;
#pragma unroll
    for (int k4 = 0; k4 < CH / 4; ++k4) {
      float4 av = ar[k4];
      acc += av.x * wr[k4 * 4 + 0];
      acc += av.y * wr[k4 * 4 + 1];
      acc += av.z * wr[k4 * 4 + 2];
      acc += av.w * wr[k4 * 4 + 3];
    }
    h2[(size_t)row * CO + j] = f2bf(acc * dinv[row]);
  }
}

// -- layer-2 agg, 8-rows-per-gather + mean-pool partial ------------------------
static __global__ __launch_bounds__(256) void k_agg32pool(const ushortT* __restrict__ h2,
                                                          const float* __restrict__ dinv,
                                                          const int* __restrict__ rowstart,
                                                          const int* __restrict__ degi,
                                                          const int* __restrict__ csr_src,
                                                          const int* __restrict__ batch,
                                                          const float* __restrict__ b2,
                                                          float* __restrict__ sums) {
  __shared__ float vals[4][CO];
  __shared__ int gid[4];
  int wave = threadIdx.x >> 6, lane = threadIdx.x & 63;
  int g = lane >> 3;          // neighbor sub-slot 0..7
  int j = lane & 7;           // ushort4 index within row (4 channels)
  int i = blockIdx.x * 4 + wave;  // grid exact: 25000*4
  const ushort4* hp = reinterpret_cast<const ushort4*>(h2);
  int s0 = rowstart[i], n = degi[i];
  float ax = 0.f, ay = 0.f, az = 0.f, aw = 0.f;
  int niter = (n + 7) >> 3;
  for (int it = 0; it < niter; ++it) {
    int kk = it * 8 + g;
    int kidx = kk < n ? kk : n - 1;
    int s = csr_src[s0 + kidx];
    float m = kk < n ? 1.0f : 0.0f;
    ushort4 hv = hp[(size_t)s * 8 + j];
    ax += m * bf2f(hv.x);
    ay += m * bf2f(hv.y);
    az += m * bf2f(hv.z);
    aw += m * bf2f(hv.w);
  }
  // reduce across the 8 lane groups (lanes with same j)
  ax += __shfl_xor(ax, 8);  ay += __shfl_xor(ay, 8);  az += __shfl_xor(az, 8);  aw += __shfl_xor(aw, 8);
  ax += __shfl_xor(ax, 16); ay += __shfl_xor(ay, 16); az += __shfl_xor(az, 16); aw += __shfl_xor(aw, 16);
  ax += __shfl_xor(ax, 32); ay += __shfl_xor(ay, 32); az += __shfl_xor(az, 32); aw += __shfl_xor(aw, 32);
  if (g == 0) {
    ushort4 sv = hp[(size_t)i * 8 + j];       // self-loop row
    float di = dinv[i];
    const float4* b2v = reinterpret_cast<const float4*>(b2);
    float4 bias = b2v[j];
    float4 o;
    o.x = (ax + bf2f(sv.x)) * di + bias.x;
    o.y = (ay + bf2f(sv.y)) * di + bias.y;
    o.z = (az + bf2f(sv.z)) * di + bias.z;
    o.w = (aw + bf2f(sv.w)) * di + bias.w;
    *reinterpret_cast<float4*>(&vals[wave][j * 4]) = o;
    if (j == 0) gid[wave] = batch[i];
  }
  __syncthreads();
  if (threadIdx.x < 32) {
    int ch = threadIdx.x;
    float run = vals[0][ch];
    int gg = gid[0];
    for (int s = 1; s < 4; ++s) {
      if (gid[s] == gg) run += vals[s][ch];
      else { atomicAdd(&sums[gg * CO + ch], run); gg = gid[s]; run = vals[s][ch]; }
    }
    atomicAdd(&sums[gg * CO + ch], run);
  }
}

static __global__ void k_final(const float* __restrict__ sums, const float* __restrict__ counts,
                               float* __restrict__ out) {
  int t = blockIdx.x * 256 + threadIdx.x;
  if (t >= NG * CO) return;
  out[t] = sums[t] / fmaxf(counts[t >> 5], 1.0f);
}

extern "C" void kernel_launch(void* const* d_in, const int* in_sizes, int n_in,
                              void* d_out, int out_size, void* d_ws, size_t ws_size,
                              hipStream_t stream) {
  const float* x   = (const float*)d_in[0];
  const int* ei    = (const int*)d_in[1];   // [2, NE]: src = ei, dst = ei+NE
  const int* batch = (const int*)d_in[2];
  const float* W1  = (const float*)d_in[3];
  const float* b1  = (const float*)d_in[4];
  const float* W2  = (const float*)d_in[5];
  const float* b2  = (const float*)d_in[6];
  float* out = (float*)d_out;

  const int* src = ei;
  const int* dst = ei + NE;

  char* base = (char*)d_ws;
  size_t off = 0;
  auto allocB = [&](size_t nbytes) {
    void* p = (void*)(base + off);
    off += ((nbytes + 255) / 256) * 256;
    return p;
  };
  int* degi      = (int*)allocB(NN * 4);
  int* rowstart  = (int*)allocB(NN * 4);
  float* dinv    = (float*)allocB(NN * 4);
  int* bsum      = (int*)allocB(NBLK * 4);
  int* bbase2    = (int*)allocB(NBLK * 4);
  int* bhist     = (int*)allocB(128 * 4);
  int* bbase     = (int*)allocB(129 * 4);
  int* bcursor   = (int*)allocB(128 * 4);
  int* csr_src   = (int*)allocB((size_t)NE * 4);          // 5 MB
  ushortT* hbuf  = (ushortT*)allocB((size_t)NN * CH * 2); // h1 bf16, then h2 bf16
  float* bufB    = (float*)allocB((size_t)NN * CH * 4);   // pairs (5 MB) then agg1 fp32
  float* sums    = (float*)allocB(NG * CO * 4);
  float* counts  = (float*)allocB(NG * 4);
  unsigned int* pairs = (unsigned int*)bufB;  // dead once k_bucket_b finishes

  dim3 B(256);
  // CSR build (bucketed, cache-friendly, packed pairs)
  k_zero<<<dim3(16), B, 0, stream>>>(sums, bhist, batch, counts);
  k_bhist<<<dim3(NBLKP), B, 0, stream>>>(dst, bhist);
  k_bscan<<<dim3(1), dim3(128), 0, stream>>>(bhist, bbase, bcursor);
  k_part<<<dim3(NBLKP), B, 0, stream>>>(src, dst, bcursor, pairs);
  k_bucket_a<<<dim3(NBUCK), B, 0, stream>>>(pairs, bbase, degi, dinv);
  k_scanA<<<dim3(NBLK), B, 0, stream>>>(degi, bsum);
  k_scanB<<<dim3(1), dim3(512), 0, stream>>>(bsum, bbase2);
  k_scanC<<<dim3(NBLK), B, 0, stream>>>(degi, bbase2, rowstart);
  k_bucket_b<<<dim3(NBUCK), B, 0, stream>>>(pairs, bbase, rowstart, csr_src);
  // layer 1
  k_gemm1<<<dim3(GGRID), B, 0, stream>>>(x, W1, dinv, hbuf);
  k_agg64<<<dim3(NN / 4), B, 0, stream>>>(hbuf, dinv, rowstart, degi, csr_src, b1, bufB);
  // layer 2 (bias+relu fused into agg64's write)
  k_gemm2<<<dim3(GGRID), B, 0, stream>>>(bufB, W2, dinv, hbuf);
  k_agg32pool<<<dim3(NN / 4), B, 0, stream>>>(hbuf, dinv, rowstart, degi, csr_src, batch, b2, sums);
  // finalize
  k_final<<<dim3((NG * CO + 255) / 256), B, 0, stream>>>(sums, counts, out);
}

// Round 19
// 246.711 us; speedup vs baseline: 1.0714x; 1.0714x over previous
//
#include <hip/hip_runtime.h>

#define NN 100000
#define NE 1250000
#define CIN 64
#define CH 64
#define CO 32
#define NG 128
#define NBLK ((NN + 255) / 256)    // 391 (node-grid for scans)
#define NBUCK 98                    // buckets of 1024 nodes: dst>>10 in [0,97]
#define BSHIFT 10
#define EPB 2048                    // edges per partition block
#define NBLKP ((NE + EPB - 1) / EPB) // 611
#define GGRID 2048                  // grid-stride GEMM grid

typedef unsigned short ushortT;

static __device__ inline ushortT f2bf(float v) {
  unsigned int u = __float_as_uint(v);
  u += 0x7FFFu + ((u >> 16) & 1u);   // round-to-nearest-even
  return (ushortT)(u >> 16);
}
static __device__ inline float bf2f(ushortT s) {
  return __uint_as_float(((unsigned int)s) << 16);
}

// ---------------- init: zero sums+bhist, per-graph counts (block 0) -----------
static __global__ void k_zero(float* __restrict__ sums, int* __restrict__ bhist,
                              const int* __restrict__ batch, float* __restrict__ counts) {
  int i = blockIdx.x * 256 + threadIdx.x;
  if (i < NG * CO) sums[i] = 0.0f;
  if (i < 128) bhist[i] = 0;
  if (blockIdx.x == 0 && threadIdx.x < NG) {
    int g = threadIdx.x;
    int lo = 0, hi = NN;
    while (lo < hi) { int m = (lo + hi) >> 1; if (batch[m] < g) lo = m + 1; else hi = m; }
    int lb = lo;
    lo = 0; hi = NN;
    while (lo < hi) { int m = (lo + hi) >> 1; if (batch[m] <= g) lo = m + 1; else hi = m; }
    counts[g] = (float)(lo - lb);
  }
}

// ---------------- bucket histogram (LDS-staged) ----------------
static __global__ __launch_bounds__(256) void k_bhist(const int* __restrict__ dst,
                                                      int* __restrict__ bhist) {
  __shared__ int lh[128];
  if (threadIdx.x < 128) lh[threadIdx.x] = 0;
  __syncthreads();
  int e0 = blockIdx.x * EPB, e1 = min(e0 + EPB, NE);
  for (int e = e0 + threadIdx.x; e < e1; e += 256)
    atomicAdd(&lh[dst[e] >> BSHIFT], 1);
  __syncthreads();
  if (threadIdx.x < 128) { int v = lh[threadIdx.x]; if (v) atomicAdd(&bhist[threadIdx.x], v); }
}

// ---------------- exclusive scan of bucket counts (1 block, 128 thr) ----------
static __global__ void k_bscan(const int* __restrict__ bhist, int* __restrict__ bbase,
                               int* __restrict__ bcursor) {
  __shared__ int tmp[128];
  int t = threadIdx.x;
  int v = bhist[t];
  tmp[t] = v;
  __syncthreads();
  for (int off = 1; off < 128; off <<= 1) {
    int a = (t >= off) ? tmp[t - off] : 0;
    __syncthreads();
    tmp[t] += a;
    __syncthreads();
  }
  int ex = tmp[t] - v;
  bbase[t] = ex;
  bcursor[t] = ex;
  if (t == 127) bbase[128] = tmp[127];  // == NE
}

// -- partition edges into bucket-grouped packed runs: pk = src | (d&1023)<<17 --
static __global__ __launch_bounds__(256) void k_part(const int* __restrict__ src,
                                                     const int* __restrict__ dst,
                                                     int* __restrict__ bcursor,
                                                     unsigned int* __restrict__ pairs) {
  __shared__ int lh[128], lbase[128], loff[128];
  if (threadIdx.x < 128) { lh[threadIdx.x] = 0; loff[threadIdx.x] = 0; }
  __syncthreads();
  int e0 = blockIdx.x * EPB, e1 = min(e0 + EPB, NE);
  for (int e = e0 + threadIdx.x; e < e1; e += 256)
    atomicAdd(&lh[dst[e] >> BSHIFT], 1);
  __syncthreads();
  if (threadIdx.x < 128) {
    int v = lh[threadIdx.x];
    lbase[threadIdx.x] = v ? atomicAdd(&bcursor[threadIdx.x], v) : 0;
  }
  __syncthreads();
  for (int e = e0 + threadIdx.x; e < e1; e += 256) {
    int d = dst[e], b = d >> BSHIFT;
    int o = atomicAdd(&loff[b], 1);
    pairs[lbase[b] + o] = (unsigned int)src[e] | ((unsigned int)(d & 1023) << 17);
  }
}

// ------- per-bucket degree via LDS histogram; coalesced degi/dinv writes ------
static __global__ __launch_bounds__(256) void k_bucket_a(const unsigned int* __restrict__ pairs,
                                                         const int* __restrict__ bbase,
                                                         int* __restrict__ degi,
                                                         float* __restrict__ dinv) {
  __shared__ int lh[1024];
  for (int t = threadIdx.x; t < 1024; t += 256) lh[t] = 0;
  __syncthreads();
  int b = blockIdx.x;
  int p0 = bbase[b], p1 = bbase[b + 1];
  for (int p = p0 + threadIdx.x; p < p1; p += 256)
    atomicAdd(&lh[pairs[p] >> 17], 1);
  __syncthreads();
  int nb = b << BSHIFT;
  for (int t = threadIdx.x; t < 1024; t += 256) {
    int node = nb + t;
    if (node < NN) { int dg = lh[t]; degi[node] = dg; dinv[node] = rsqrtf((float)dg + 1.0f); }
  }
}

// ---------------- prefix scan of degrees -> CSR row starts ----------------
static __global__ void k_scanA(const int* __restrict__ degi, int* __restrict__ bsum) {
  __shared__ int tmp[256];
  int i = blockIdx.x * 256 + threadIdx.x;
  int v = (i < NN) ? degi[i] : 0;
  tmp[threadIdx.x] = v;
  __syncthreads();
  for (int off = 128; off > 0; off >>= 1) {
    if (threadIdx.x < off) tmp[threadIdx.x] += tmp[threadIdx.x + off];
    __syncthreads();
  }
  if (threadIdx.x == 0) bsum[blockIdx.x] = tmp[0];
}

static __global__ void k_scanB(const int* __restrict__ bsum, int* __restrict__ bbase2) {
  __shared__ int tmp[512];
  int t = threadIdx.x;
  int v = (t < NBLK) ? bsum[t] : 0;
  tmp[t] = v;
  __syncthreads();
  for (int off = 1; off < 512; off <<= 1) {
    int add = (t >= off) ? tmp[t - off] : 0;
    __syncthreads();
    tmp[t] += add;
    __syncthreads();
  }
  if (t < NBLK) bbase2[t] = tmp[t] - v;  // exclusive
}

static __global__ void k_scanC(const int* __restrict__ degi, const int* __restrict__ bbase2,
                               int* __restrict__ rowstart) {
  __shared__ int tmp[256];
  int i = blockIdx.x * 256 + threadIdx.x;
  int v = (i < NN) ? degi[i] : 0;
  tmp[threadIdx.x] = v;
  __syncthreads();
  for (int off = 1; off < 256; off <<= 1) {
    int add = (threadIdx.x >= off) ? tmp[threadIdx.x - off] : 0;
    __syncthreads();
    tmp[threadIdx.x] += add;
    __syncthreads();
  }
  if (i < NN) rowstart[i] = bbase2[blockIdx.x] + tmp[threadIdx.x] - v;  // exclusive
}

// ------- per-bucket CSR scatter with LDS cursors (localized writes) -----------
static __global__ __launch_bounds__(256) void k_bucket_b(const unsigned int* __restrict__ pairs,
                                                         const int* __restrict__ bbase,
                                                         const int* __restrict__ rowstart,
                                                         int* __restrict__ csr_src) {
  __shared__ int cur[1024];
  int b = blockIdx.x, nb = b << BSHIFT;
  for (int t = threadIdx.x; t < 1024; t += 256) {
    int node = nb + t;
    cur[t] = (node < NN) ? rowstart[node] : 0;
  }
  __syncthreads();
  int p0 = bbase[b], p1 = bbase[b + 1];
  for (int p = p0 + threadIdx.x; p < p1; p += 256) {
    unsigned int pk = pairs[p];
    int pos = atomicAdd(&cur[pk >> 17], 1);
    csr_src[pos] = (int)(pk & 0x1FFFFu);
  }
}

// -- GEMM 1: h' = bf16(dinv*(x @ W1)); W col in regs; x row via SCALAR loads ---
static __global__ __launch_bounds__(256) void k_gemm1(const float* __restrict__ x,
                                                      const float* __restrict__ W,
                                                      const float* __restrict__ dinv,
                                                      ushortT* __restrict__ h) {
  int wave = threadIdx.x >> 6;
  int lane = threadIdx.x & 63;
  float wr[CIN];
#pragma unroll
  for (int k = 0; k < CIN; ++k) wr[k] = W[k * CH + lane];  // coalesced, once
  for (int row0 = blockIdx.x * 4 + wave; row0 < NN; row0 += GGRID * 4) {
    int row = __builtin_amdgcn_readfirstlane(row0);
    const float4* xr = reinterpret_cast<const float4*>(x + (size_t)row * CIN);
    float dv = dinv[row];  // uniform -> scalar load
    float a0 = 0.f, a1 = 0.f, a2 = 0.f, a3 = 0.f;
#pragma unroll
    for (int k4 = 0; k4 < CIN / 4; k4 += 4) {
      float4 v0 = xr[k4 + 0];
      float4 v1 = xr[k4 + 1];
      float4 v2 = xr[k4 + 2];
      float4 v3 = xr[k4 + 3];
      a0 += v0.x * wr[4 * k4 + 0] + v0.y * wr[4 * k4 + 1] + v0.z * wr[4 * k4 + 2] + v0.w * wr[4 * k4 + 3];
      a1 += v1.x * wr[4 * k4 + 4] + v1.y * wr[4 * k4 + 5] + v1.z * wr[4 * k4 + 6] + v1.w * wr[4 * k4 + 7];
      a2 += v2.x * wr[4 * k4 + 8] + v2.y * wr[4 * k4 + 9] + v2.z * wr[4 * k4 + 10] + v2.w * wr[4 * k4 + 11];
      a3 += v3.x * wr[4 * k4 + 12] + v3.y * wr[4 * k4 + 13] + v3.z * wr[4 * k4 + 14] + v3.w * wr[4 * k4 + 15];
    }
    h[(size_t)row * CH + lane] = f2bf(((a0 + a1) + (a2 + a3)) * dv);
  }
}

// -- layer-1 agg: uniform node per wave; indices via batched SCALAR loads ------
// out = relu(dinv*(self + sum_nbrs) + b1)
static __global__ __launch_bounds__(256) void k_agg64(const ushortT* __restrict__ h,
                                                      const float* __restrict__ dinv,
                                                      const int* __restrict__ rowstart,
                                                      const int* __restrict__ degi,
                                                      const int* __restrict__ csr_src,
                                                      const float* __restrict__ b1,
                                                      float* __restrict__ agg) {
  int wave = threadIdx.x >> 6, lane = threadIdx.x & 63;
  int i = __builtin_amdgcn_readfirstlane(blockIdx.x * 4 + wave);  // uniform node
  float bias = b1[lane];
  float acc = bf2f(h[(size_t)i * CH + lane]);   // self-loop (h already dinv-scaled)
  int s0 = rowstart[i], n = degi[i];            // scalar loads (uniform addr)
  int k = 0;
  for (; k + 8 <= n; k += 8) {
    // uniform addresses -> batched s_load; 8 independent gathers follow
    int i0 = csr_src[s0 + k + 0];
    int i1 = csr_src[s0 + k + 1];
    int i2 = csr_src[s0 + k + 2];
    int i3 = csr_src[s0 + k + 3];
    int i4 = csr_src[s0 + k + 4];
    int i5 = csr_src[s0 + k + 5];
    int i6 = csr_src[s0 + k + 6];
    int i7 = csr_src[s0 + k + 7];
    float a0 = bf2f(h[(size_t)i0 * CH + lane]);
    float a1 = bf2f(h[(size_t)i1 * CH + lane]);
    float a2 = bf2f(h[(size_t)i2 * CH + lane]);
    float a3 = bf2f(h[(size_t)i3 * CH + lane]);
    float a4 = bf2f(h[(size_t)i4 * CH + lane]);
    float a5 = bf2f(h[(size_t)i5 * CH + lane]);
    float a6 = bf2f(h[(size_t)i6 * CH + lane]);
    float a7 = bf2f(h[(size_t)i7 * CH + lane]);
    acc += ((a0 + a1) + (a2 + a3)) + ((a4 + a5) + (a6 + a7));
  }
  for (; k < n; ++k) acc += bf2f(h[(size_t)csr_src[s0 + k] * CH + lane]);
  float v = acc * dinv[i] + bias;
  agg[(size_t)i * CH + lane] = v > 0.0f ? v : 0.0f;
}

// -- GEMM 2: h2' = bf16(dinv*(aggRelu @ W2)); W2 column in 64 registers --------
static __global__ __launch_bounds__(256) void k_gemm2(const float* __restrict__ agg1,
                                                      const float* __restrict__ W,
                                                      const float* __restrict__ dinv,
                                                      ushortT* __restrict__ h2) {
  int half = threadIdx.x >> 5;
  int j = threadIdx.x & 31;
  float wr[CH];
#pragma unroll
  for (int k = 0; k < CH; ++k) wr[k] = W[k * CO + j];  // coalesced, once
  for (int row = blockIdx.x * 8 + half; row < NN; row += GGRID * 8) {
    const float4* ar = reinterpret_cast<const float4*>(agg1 + (size_t)row * CH);
    float acc = 0.0f;
#pragma unroll
    for (int k4 = 0; k4 < CH / 4; ++k4) {
      float4 av = ar[k4];
      acc += av.x * wr[k4 * 4 + 0];
      acc += av.y * wr[k4 * 4 + 1];
      acc += av.z * wr[k4 * 4 + 2];
      acc += av.w * wr[k4 * 4 + 3];
    }
    h2[(size_t)row * CO + j] = f2bf(acc * dinv[row]);
  }
}

// -- layer-2 agg: uniform node/wave; g=lane>>5 picks even/odd neighbor ---------
static __global__ __launch_bounds__(256) void k_agg32pool(const ushortT* __restrict__ h2,
                                                          const float* __restrict__ dinv,
                                                          const int* __restrict__ rowstart,
                                                          const int* __restrict__ degi,
                                                          const int* __restrict__ csr_src,
                                                          const int* __restrict__ batch,
                                                          const float* __restrict__ b2,
                                                          float* __restrict__ sums) {
  __shared__ float vals[4][CO];
  __shared__ int gid[4];
  int wave = threadIdx.x >> 6, lane = threadIdx.x & 63;
  int g = lane >> 5;          // neighbor parity 0/1
  int j = lane & 31;          // channel
  int i = __builtin_amdgcn_readfirstlane(blockIdx.x * 4 + wave);  // uniform node
  int s0 = rowstart[i], n = degi[i];  // scalar loads
  float acc = 0.0f;
  int k = 0;
  for (; k + 8 <= n; k += 8) {
    int i0 = csr_src[s0 + k + 0];
    int i1 = csr_src[s0 + k + 1];
    int i2 = csr_src[s0 + k + 2];
    int i3 = csr_src[s0 + k + 3];
    int i4 = csr_src[s0 + k + 4];
    int i5 = csr_src[s0 + k + 5];
    int i6 = csr_src[s0 + k + 6];
    int i7 = csr_src[s0 + k + 7];
    int sa = g ? i1 : i0;
    int sb = g ? i3 : i2;
    int sc = g ? i5 : i4;
    int sd = g ? i7 : i6;
    float a = bf2f(h2[(size_t)sa * CO + j]);
    float b = bf2f(h2[(size_t)sb * CO + j]);
    float c = bf2f(h2[(size_t)sc * CO + j]);
    float d = bf2f(h2[(size_t)sd * CO + j]);
    acc += (a + b) + (c + d);
  }
  for (; k + 2 <= n; k += 2) {
    int i0 = csr_src[s0 + k];
    int i1 = csr_src[s0 + k + 1];
    int s = g ? i1 : i0;
    acc += bf2f(h2[(size_t)s * CO + j]);
  }
  if (k < n) {
    int s = csr_src[s0 + k];
    if (g == 0) acc += bf2f(h2[(size_t)s * CO + j]);
  }
  acc += __shfl_xor(acc, 32);   // combine neighbor parities
  if (g == 0) {
    acc += bf2f(h2[(size_t)i * CO + j]);  // self-loop
    vals[wave][j] = acc * dinv[i] + b2[j];
    if (j == 0) gid[wave] = batch[i];
  }
  __syncthreads();
  if (threadIdx.x < 32) {
    int ch = threadIdx.x;
    float run = vals[0][ch];
    int gg = gid[0];
    for (int s = 1; s < 4; ++s) {
      if (gid[s] == gg) run += vals[s][ch];
      else { atomicAdd(&sums[gg * CO + ch], run); gg = gid[s]; run = vals[s][ch]; }
    }
    atomicAdd(&sums[gg * CO + ch], run);
  }
}

static __global__ void k_final(const float* __restrict__ sums, const float* __restrict__ counts,
                               float* __restrict__ out) {
  int t = blockIdx.x * 256 + threadIdx.x;
  if (t >= NG * CO) return;
  out[t] = sums[t] / fmaxf(counts[t >> 5], 1.0f);
}

extern "C" void kernel_launch(void* const* d_in, const int* in_sizes, int n_in,
                              void* d_out, int out_size, void* d_ws, size_t ws_size,
                              hipStream_t stream) {
  const float* x   = (const float*)d_in[0];
  const int* ei    = (const int*)d_in[1];   // [2, NE]: src = ei, dst = ei+NE
  const int* batch = (const int*)d_in[2];
  const float* W1  = (const float*)d_in[3];
  const float* b1  = (const float*)d_in[4];
  const float* W2  = (const float*)d_in[5];
  const float* b2  = (const float*)d_in[6];
  float* out = (float*)d_out;

  const int* src = ei;
  const int* dst = ei + NE;

  char* base = (char*)d_ws;
  size_t off = 0;
  auto allocB = [&](size_t nbytes) {
    void* p = (void*)(base + off);
    off += ((nbytes + 255) / 256) * 256;
    return p;
  };
  int* degi      = (int*)allocB(NN * 4);
  int* rowstart  = (int*)allocB(NN * 4);
  float* dinv    = (float*)allocB(NN * 4);
  int* bsum      = (int*)allocB(NBLK * 4);
  int* bbase2    = (int*)allocB(NBLK * 4);
  int* bhist     = (int*)allocB(128 * 4);
  int* bbase     = (int*)allocB(129 * 4);
  int* bcursor   = (int*)allocB(128 * 4);
  int* csr_src   = (int*)allocB((size_t)NE * 4);          // 5 MB
  ushortT* hbuf  = (ushortT*)allocB((size_t)NN * CH * 2); // h1 bf16, then h2 bf16
  float* bufB    = (float*)allocB((size_t)NN * CH * 4);   // pairs (5 MB) then agg1 fp32
  float* sums    = (float*)allocB(NG * CO * 4);
  float* counts  = (float*)allocB(NG * 4);
  unsigned int* pairs = (unsigned int*)bufB;  // dead once k_bucket_b finishes

  dim3 B(256);
  // CSR build (bucketed, cache-friendly, packed pairs)
  k_zero<<<dim3(16), B, 0, stream>>>(sums, bhist, batch, counts);
  k_bhist<<<dim3(NBLKP), B, 0, stream>>>(dst, bhist);
  k_bscan<<<dim3(1), dim3(128), 0, stream>>>(bhist, bbase, bcursor);
  k_part<<<dim3(NBLKP), B, 0, stream>>>(src, dst, bcursor, pairs);
  k_bucket_a<<<dim3(NBUCK), B, 0, stream>>>(pairs, bbase, degi, dinv);
  k_scanA<<<dim3(NBLK), B, 0, stream>>>(degi, bsum);
  k_scanB<<<dim3(1), dim3(512), 0, stream>>>(bsum, bbase2);
  k_scanC<<<dim3(NBLK), B, 0, stream>>>(degi, bbase2, rowstart);
  k_bucket_b<<<dim3(NBUCK), B, 0, stream>>>(pairs, bbase, rowstart, csr_src);
  // layer 1
  k_gemm1<<<dim3(GGRID), B, 0, stream>>>(x, W1, dinv, hbuf);
  k_agg64<<<dim3(NN / 4), B, 0, stream>>>(hbuf, dinv, rowstart, degi, csr_src, b1, bufB);
  // layer 2 (bias+relu fused into agg64's write)
  k_gemm2<<<dim3(GGRID), B, 0, stream>>>(bufB, W2, dinv, hbuf);
  k_agg32pool<<<dim3(NN / 4), B, 0, stream>>>(hbuf, dinv, rowstart, degi, csr_src, batch, b2, sums);
  // finalize
  k_final<<<dim3((NG * CO + 255) / 256), B, 0, stream>>>(sums, counts, out);
}

// Round 21
// 215.117 us; speedup vs baseline: 1.2288x; 1.1469x over previous
//
#include <hip/hip_runtime.h>

#define NN 100000
#define NE 1250000
#define CIN 64
#define CH 64
#define CO 32
#define NG 128
#define NBUCK 98                     // buckets of 1024 nodes: dst>>10 in [0,97]
#define BSHIFT 10
#define EPB 2048                     // edges per partition block
#define NBLKP ((NE + EPB - 1) / EPB) // 611
#define GGRID 2048                   // grid-stride GEMM grid
#define CSRCAP (NE + NBUCK * 8192)   // padded CSR capacity

typedef unsigned short ushortT;

static __device__ inline ushortT f2bf(float v) {
  unsigned int u = __float_as_uint(v);
  u += 0x7FFFu + ((u >> 16) & 1u);   // round-to-nearest-even
  return (ushortT)(u >> 16);
}
static __device__ inline float bf2f(ushortT s) {
  return __uint_as_float(((unsigned int)s) << 16);
}

// ---------------- init: zero sums+bhist, per-graph counts (block 0) -----------
static __global__ void k_zero(float* __restrict__ sums, int* __restrict__ bhist,
                              const int* __restrict__ batch, float* __restrict__ counts) {
  int i = blockIdx.x * 256 + threadIdx.x;
  if (i < NG * CO) sums[i] = 0.0f;
  if (i < 128) bhist[i] = 0;
  if (blockIdx.x == 0 && threadIdx.x < NG) {
    int g = threadIdx.x;
    int lo = 0, hi = NN;
    while (lo < hi) { int m = (lo + hi) >> 1; if (batch[m] < g) lo = m + 1; else hi = m; }
    int lb = lo;
    lo = 0; hi = NN;
    while (lo < hi) { int m = (lo + hi) >> 1; if (batch[m] <= g) lo = m + 1; else hi = m; }
    counts[g] = (float)(lo - lb);
  }
}

// ---------------- bucket histogram (LDS-staged) ----------------
static __global__ __launch_bounds__(256) void k_bhist(const int* __restrict__ dst,
                                                      int* __restrict__ bhist) {
  __shared__ int lh[128];
  if (threadIdx.x < 128) lh[threadIdx.x] = 0;
  __syncthreads();
  int e0 = blockIdx.x * EPB, e1 = min(e0 + EPB, NE);
  for (int e = e0 + threadIdx.x; e < e1; e += 256)
    atomicAdd(&lh[dst[e] >> BSHIFT], 1);
  __syncthreads();
  if (threadIdx.x < 128) { int v = lh[threadIdx.x]; if (v) atomicAdd(&bhist[threadIdx.x], v); }
}

// ---------------- exclusive scan of bucket counts (1 block, 128 thr) ----------
static __global__ void k_bscan(const int* __restrict__ bhist, int* __restrict__ bbase,
                               int* __restrict__ bcursor) {
  __shared__ int tmp[128];
  int t = threadIdx.x;
  int v = bhist[t];
  tmp[t] = v;
  __syncthreads();
  for (int off = 1; off < 128; off <<= 1) {
    int a = (t >= off) ? tmp[t - off] : 0;
    __syncthreads();
    tmp[t] += a;
    __syncthreads();
  }
  int ex = tmp[t] - v;
  bbase[t] = ex;
  bcursor[t] = ex;
  if (t == 127) bbase[128] = tmp[127];  // == NE
}

// -- partition edges into bucket-grouped packed runs: pk = src | (d&1023)<<17 --
static __global__ __launch_bounds__(256) void k_part(const int* __restrict__ src,
                                                     const int* __restrict__ dst,
                                                     int* __restrict__ bcursor,
                                                     unsigned int* __restrict__ pairs) {
  __shared__ int lh[128], lbase[128], loff[128];
  if (threadIdx.x < 128) { lh[threadIdx.x] = 0; loff[threadIdx.x] = 0; }
  __syncthreads();
  int e0 = blockIdx.x * EPB, e1 = min(e0 + EPB, NE);
  for (int e = e0 + threadIdx.x; e < e1; e += 256)
    atomicAdd(&lh[dst[e] >> BSHIFT], 1);
  __syncthreads();
  if (threadIdx.x < 128) {
    int v = lh[threadIdx.x];
    lbase[threadIdx.x] = v ? atomicAdd(&bcursor[threadIdx.x], v) : 0;
  }
  __syncthreads();
  for (int e = e0 + threadIdx.x; e < e1; e += 256) {
    int d = dst[e], b = d >> BSHIFT;
    int o = atomicAdd(&loff[b], 1);
    pairs[lbase[b] + o] = (unsigned int)src[e] | ((unsigned int)(d & 1023) << 17);
  }
}

// -- fused per-bucket: degree hist -> in-LDS scan (padded to 8) -> CSR scatter -
// rowstart = padded base; degi = niter (padded/8); pad slots point at zero row NN
static __global__ __launch_bounds__(1024) void k_bucket(const unsigned int* __restrict__ pairs,
                                                        const int* __restrict__ bbase,
                                                        int* __restrict__ rowstart,
                                                        int* __restrict__ degi,
                                                        float* __restrict__ dinv,
                                                        int* __restrict__ csr_src) {
  __shared__ int lh[1024];
  __shared__ int tmp[1024];
  __shared__ int cur[1024];
  int t = threadIdx.x;
  int b = blockIdx.x, nb = b << BSHIFT;
  lh[t] = 0;
  __syncthreads();
  int p0 = bbase[b], p1 = bbase[b + 1];
  for (int p = p0 + t; p < p1; p += 1024)
    atomicAdd(&lh[pairs[p] >> 17], 1);
  __syncthreads();
  int node = nb + t;
  int raw = lh[t];
  int pd = (raw + 7) & ~7;          // pad to multiple of 8
  tmp[t] = pd;
  __syncthreads();
  for (int off = 1; off < 1024; off <<= 1) {
    int add = (t >= off) ? tmp[t - off] : 0;
    __syncthreads();
    tmp[t] += add;
    __syncthreads();
  }
  int ex = tmp[t] - pd;             // exclusive padded prefix within bucket
  int rs = p0 + b * 8192 + ex;      // padded base: raw base + per-bucket slack
  if (node < NN) {
    rowstart[node] = rs;
    degi[node] = pd >> 3;           // niter (groups of 8)
    dinv[node] = rsqrtf((float)raw + 1.0f);
  }
  cur[t] = rs;
  __syncthreads();
  for (int p = p0 + t; p < p1; p += 1024) {
    unsigned int pk = pairs[p];
    int pos = atomicAdd(&cur[pk >> 17], 1);
    csr_src[pos] = (int)(pk & 0x1FFFFu);
  }
  __syncthreads();
  for (int q = raw; q < pd; ++q) csr_src[rs + q] = NN;  // sentinel fill
}

// -- GEMM 1: h' = bf16(dinv*(x @ W1)); W col in regs; x row via SCALAR loads ---
static __global__ __launch_bounds__(256) void k_gemm1(const float* __restrict__ x,
                                                      const float* __restrict__ W,
                                                      const float* __restrict__ dinv,
                                                      ushortT* __restrict__ h) {
  if (blockIdx.x == 0 && threadIdx.x < CH) h[(size_t)NN * CH + threadIdx.x] = 0;  // zero pad row
  int wave = threadIdx.x >> 6;
  int lane = threadIdx.x & 63;
  float wr[CIN];
#pragma unroll
  for (int k = 0; k < CIN; ++k) wr[k] = W[k * CH + lane];  // coalesced, once
  for (int row0 = blockIdx.x * 4 + wave; row0 < NN; row0 += GGRID * 4) {
    int row = __builtin_amdgcn_readfirstlane(row0);
    const float4* xr = reinterpret_cast<const float4*>(x + (size_t)row * CIN);
    float dv = dinv[row];  // uniform -> scalar load
    float a0 = 0.f, a1 = 0.f, a2 = 0.f, a3 = 0.f;
#pragma unroll
    for (int k4 = 0; k4 < CIN / 4; k4 += 4) {
      float4 v0 = xr[k4 + 0];
      float4 v1 = xr[k4 + 1];
      float4 v2 = xr[k4 + 2];
      float4 v3 = xr[k4 + 3];
      a0 += v0.x * wr[4 * k4 + 0] + v0.y * wr[4 * k4 + 1] + v0.z * wr[4 * k4 + 2] + v0.w * wr[4 * k4 + 3];
      a1 += v1.x * wr[4 * k4 + 4] + v1.y * wr[4 * k4 + 5] + v1.z * wr[4 * k4 + 6] + v1.w * wr[4 * k4 + 7];
      a2 += v2.x * wr[4 * k4 + 8] + v2.y * wr[4 * k4 + 9] + v2.z * wr[4 * k4 + 10] + v2.w * wr[4 * k4 + 11];
      a3 += v3.x * wr[4 * k4 + 12] + v3.y * wr[4 * k4 + 13] + v3.z * wr[4 * k4 + 14] + v3.w * wr[4 * k4 + 15];
    }
    h[(size_t)row * CH + lane] = f2bf(((a0 + a1) + (a2 + a3)) * dv);
  }
}

// -- layer-1 agg: uniform node/wave; padded rows -> tail-free 8-wide loop ------
static __global__ __launch_bounds__(256) void k_agg64(const ushortT* __restrict__ h,
                                                      const float* __restrict__ dinv,
                                                      const int* __restrict__ rowstart,
                                                      const int* __restrict__ degi,
                                                      const int* __restrict__ csr_src,
                                                      const float* __restrict__ b1,
                                                      float* __restrict__ agg) {
  int wave = threadIdx.x >> 6, lane = threadIdx.x & 63;
  int i = __builtin_amdgcn_readfirstlane(blockIdx.x * 4 + wave);  // uniform node
  float bias = b1[lane];
  float acc = bf2f(h[(size_t)i * CH + lane]);   // self-loop (h already dinv-scaled)
  int s0 = rowstart[i], niter = degi[i];        // scalar loads (uniform addr)
  for (int it = 0; it < niter; ++it) {
    int base = s0 + it * 8;
    int i0 = csr_src[base + 0];
    int i1 = csr_src[base + 1];
    int i2 = csr_src[base + 2];
    int i3 = csr_src[base + 3];
    int i4 = csr_src[base + 4];
    int i5 = csr_src[base + 5];
    int i6 = csr_src[base + 6];
    int i7 = csr_src[base + 7];
    float a0 = bf2f(h[(size_t)i0 * CH + lane]);
    float a1 = bf2f(h[(size_t)i1 * CH + lane]);
    float a2 = bf2f(h[(size_t)i2 * CH + lane]);
    float a3 = bf2f(h[(size_t)i3 * CH + lane]);
    float a4 = bf2f(h[(size_t)i4 * CH + lane]);
    float a5 = bf2f(h[(size_t)i5 * CH + lane]);
    float a6 = bf2f(h[(size_t)i6 * CH + lane]);
    float a7 = bf2f(h[(size_t)i7 * CH + lane]);
    acc += ((a0 + a1) + (a2 + a3)) + ((a4 + a5) + (a6 + a7));
  }
  float v = acc * dinv[i] + bias;
  agg[(size_t)i * CH + lane] = v > 0.0f ? v : 0.0f;
}

// -- GEMM 2: h2' = bf16(dinv*(aggRelu @ W2)); W2 column in 64 registers --------
static __global__ __launch_bounds__(256) void k_gemm2(const float* __restrict__ agg1,
                                                      const float* __restrict__ W,
                                                      const float* __restrict__ dinv,
                                                      ushortT* __restrict__ h2) {
  if (blockIdx.x == 0 && threadIdx.x < CO) h2[(size_t)NN * CO + threadIdx.x] = 0;  // zero pad row
  int half = threadIdx.x >> 5;
  int j = threadIdx.x & 31;
  float wr[CH];
#pragma unroll
  for (int k = 0; k < CH; ++k) wr[k] = W[k * CO + j];  // coalesced, once
  for (int row = blockIdx.x * 8 + half; row < NN; row += GGRID * 8) {
    const float4* ar = reinterpret_cast<const float4*>(agg1 + (size_t)row * CH);
    float acc = 0.0f;
#pragma unroll
    for (int k4 = 0; k4 < CH / 4; ++k4) {
      float4 av = ar[k4];
      acc += av.x * wr[k4 * 4 + 0];
      acc += av.y * wr[k4 * 4 + 1];
      acc += av.z * wr[k4 * 4 + 2];
      acc += av.w * wr[k4 * 4 + 3];
    }
    h2[(size_t)row * CO + j] = f2bf(acc * dinv[row]);
  }
}

// -- layer-2 agg: uniform node/wave; parity split; tail-free padded loop -------
static __global__ __launch_bounds__(256) void k_agg32pool(const ushortT* __restrict__ h2,
                                                          const float* __restrict__ dinv,
                                                          const int* __restrict__ rowstart,
                                                          const int* __restrict__ degi,
                                                          const int* __restrict__ csr_src,
                                                          const int* __restrict__ batch,
                                                          const float* __restrict__ b2,
                                                          float* __restrict__ sums) {
  __shared__ float vals[4][CO];
  __shared__ int gid[4];
  int wave = threadIdx.x >> 6, lane = threadIdx.x & 63;
  int g = lane >> 5;          // neighbor parity 0/1
  int j = lane & 31;          // channel
  int i = __builtin_amdgcn_readfirstlane(blockIdx.x * 4 + wave);  // uniform node
  int s0 = rowstart[i], niter = degi[i];  // scalar loads
  float acc = 0.0f;
  for (int it = 0; it < niter; ++it) {
    int base = s0 + it * 8;
    int i0 = csr_src[base + 0];
    int i1 = csr_src[base + 1];
    int i2 = csr_src[base + 2];
    int i3 = csr_src[base + 3];
    int i4 = csr_src[base + 4];
    int i5 = csr_src[base + 5];
    int i6 = csr_src[base + 6];
    int i7 = csr_src[base + 7];
    int sa = g ? i1 : i0;
    int sb = g ? i3 : i2;
    int sc = g ? i5 : i4;
    int sd = g ? i7 : i6;
    float a = bf2f(h2[(size_t)sa * CO + j]);
    float b = bf2f(h2[(size_t)sb * CO + j]);
    float c = bf2f(h2[(size_t)sc * CO + j]);
    float d = bf2f(h2[(size_t)sd * CO + j]);
    acc += (a + b) + (c + d);
  }
  acc += __shfl_xor(acc, 32);   // combine neighbor parities
  if (g == 0) {
    acc += bf2f(h2[(size_t)i * CO + j]);  // self-loop
    vals[wave][j] = acc * dinv[i] + b2[j];
    if (j == 0) gid[wave] = batch[i];
  }
  __syncthreads();
  if (threadIdx.x < 32) {
    int ch = threadIdx.x;
    float run = vals[0][ch];
    int gg = gid[0];
    for (int s = 1; s < 4; ++s) {
      if (gid[s] == gg) run += vals[s][ch];
      else { atomicAdd(&sums[gg * CO + ch], run); gg = gid[s]; run = vals[s][ch]; }
    }
    atomicAdd(&sums[gg * CO + ch], run);
  }
}

static __global__ void k_final(const float* __restrict__ sums, const float* __restrict__ counts,
                               float* __restrict__ out) {
  int t = blockIdx.x * 256 + threadIdx.x;
  if (t >= NG * CO) return;
  out[t] = sums[t] / fmaxf(counts[t >> 5], 1.0f);
}

extern "C" void kernel_launch(void* const* d_in, const int* in_sizes, int n_in,
                              void* d_out, int out_size, void* d_ws, size_t ws_size,
                              hipStream_t stream) {
  const float* x   = (const float*)d_in[0];
  const int* ei    = (const int*)d_in[1];   // [2, NE]: src = ei, dst = ei+NE
  const int* batch = (const int*)d_in[2];
  const float* W1  = (const float*)d_in[3];
  const float* b1  = (const float*)d_in[4];
  const float* W2  = (const float*)d_in[5];
  const float* b2  = (const float*)d_in[6];
  float* out = (float*)d_out;

  const int* src = ei;
  const int* dst = ei + NE;

  char* base = (char*)d_ws;
  size_t off = 0;
  auto allocB = [&](size_t nbytes) {
    void* p = (void*)(base + off);
    off += ((nbytes + 255) / 256) * 256;
    return p;
  };
  int* degi      = (int*)allocB(NN * 4);
  int* rowstart  = (int*)allocB(NN * 4);
  float* dinv    = (float*)allocB(NN * 4);
  int* bhist     = (int*)allocB(128 * 4);
  int* bbase     = (int*)allocB(129 * 4);
  int* bcursor   = (int*)allocB(128 * 4);
  int* csr_src   = (int*)allocB((size_t)CSRCAP * 4);          // 8.2 MB (padded)
  ushortT* hbuf  = (ushortT*)allocB((size_t)(NN + 1) * CH * 2); // h1 bf16 (+zero row), h2 reuses
  float* bufB    = (float*)allocB((size_t)NN * CH * 4);       // pairs (5 MB) then agg1 fp32
  float* sums    = (float*)allocB(NG * CO * 4);
  float* counts  = (float*)allocB(NG * 4);
  unsigned int* pairs = (unsigned int*)bufB;  // dead once k_bucket finishes

  dim3 B(256);
  // CSR build (bucketed, fused scan+scatter, padded rows)
  k_zero<<<dim3(16), B, 0, stream>>>(sums, bhist, batch, counts);
  k_bhist<<<dim3(NBLKP), B, 0, stream>>>(dst, bhist);
  k_bscan<<<dim3(1), dim3(128), 0, stream>>>(bhist, bbase, bcursor);
  k_part<<<dim3(NBLKP), B, 0, stream>>>(src, dst, bcursor, pairs);
  k_bucket<<<dim3(NBUCK), dim3(1024), 0, stream>>>(pairs, bbase, rowstart, degi, dinv, csr_src);
  // layer 1
  k_gemm1<<<dim3(GGRID), B, 0, stream>>>(x, W1, dinv, hbuf);
  k_agg64<<<dim3(NN / 4), B, 0, stream>>>(hbuf, dinv, rowstart, degi, csr_src, b1, bufB);
  // layer 2 (bias+relu fused into agg64's write)
  k_gemm2<<<dim3(GGRID), B, 0, stream>>>(bufB, W2, dinv, hbuf);
  k_agg32pool<<<dim3(NN / 4), B, 0, stream>>>(hbuf, dinv, rowstart, degi, csr_src, batch, b2, sums);
  // finalize
  k_final<<<dim3((NG * CO + 255) / 256), B, 0, stream>>>(sums, counts, out);
}

// Round 22
// 160.633 us; speedup vs baseline: 1.6456x; 1.3392x over previous
//
#include <hip/hip_runtime.h>

#define NN 100000
#define NE 1250000
#define CIN 64
#define CH 64
#define CO 32
#define NG 128
#define NBUCK 98                     // buckets of 1024 nodes: dst>>10 in [0,97]
#define BSHIFT 10
#define EPB 2048                     // edges per partition block
#define NBLKP ((NE + EPB - 1) / EPB) // 611
#define PSLOT 16384                  // pairs slots per bucket (max count ~13.4K)
#define CSLOT 24576                  // csr slots per bucket (count + pad <= 20.6K)
#define NTILE (NN / 16)              // 6250 MFMA row-tiles
#define GB ((NTILE + 3) / 4)         // 1563 blocks, 4 waves each

typedef unsigned short ushortT;
typedef __attribute__((ext_vector_type(8))) short bfrag;   // 8 bf16 (4 VGPR)
typedef __attribute__((ext_vector_type(4))) float ffrag;   // 4 fp32 acc

static __device__ inline ushortT f2bf(float v) {
  unsigned int u = __float_as_uint(v);
  u += 0x7FFFu + ((u >> 16) & 1u);   // round-to-nearest-even
  return (ushortT)(u >> 16);
}
static __device__ inline float bf2f(ushortT s) {
  return __uint_as_float(((unsigned int)s) << 16);
}
static __device__ inline bfrag pack8(float4 lo, float4 hi) {
  bfrag r;
  r[0] = (short)f2bf(lo.x); r[1] = (short)f2bf(lo.y);
  r[2] = (short)f2bf(lo.z); r[3] = (short)f2bf(lo.w);
  r[4] = (short)f2bf(hi.x); r[5] = (short)f2bf(hi.y);
  r[6] = (short)f2bf(hi.z); r[7] = (short)f2bf(hi.w);
  return r;
}

// -- init: sums, bucket cursors, counts, bf16-transposed weights, h1 sentinel --
static __global__ void k_zero(float* __restrict__ sums, int* __restrict__ bcursor,
                              const int* __restrict__ batch, float* __restrict__ counts,
                              const float* __restrict__ W1, ushortT* __restrict__ W1T,
                              const float* __restrict__ W2, ushortT* __restrict__ W2T,
                              ushortT* __restrict__ h) {
  int i = blockIdx.x * 256 + threadIdx.x;  // grid 16*256 = 4096
  if (i < NG * CO) sums[i] = 0.0f;
  if (i < 128) bcursor[i] = i * PSLOT;
  if (i < CH) h[(size_t)NN * CH + i] = 0;                    // h1 sentinel row
  if (i < CIN * CH) W1T[i] = f2bf(W1[(i & 63) * CH + (i >> 6)]);   // W1T[n][k]
  if (i < CH * CO) W2T[i] = f2bf(W2[(i & 63) * CO + (i >> 6)]);    // W2T[n][k]
  if (blockIdx.x == 0 && threadIdx.x < NG) {
    int g = threadIdx.x;
    int lo = 0, hi = NN;
    while (lo < hi) { int m = (lo + hi) >> 1; if (batch[m] < g) lo = m + 1; else hi = m; }
    int lb = lo;
    lo = 0; hi = NN;
    while (lo < hi) { int m = (lo + hi) >> 1; if (batch[m] <= g) lo = m + 1; else hi = m; }
    counts[g] = (float)(lo - lb);
  }
}

// -- partition edges into fixed-slot bucket runs: pk = src | (d&1023)<<17 ------
static __global__ __launch_bounds__(256) void k_part(const int* __restrict__ src,
                                                     const int* __restrict__ dst,
                                                     int* __restrict__ bcursor,
                                                     unsigned int* __restrict__ pairs) {
  __shared__ int lh[128], lbase[128], loff[128];
  if (threadIdx.x < 128) { lh[threadIdx.x] = 0; loff[threadIdx.x] = 0; }
  __syncthreads();
  int e0 = blockIdx.x * EPB, e1 = min(e0 + EPB, NE);
  for (int e = e0 + threadIdx.x; e < e1; e += 256)
    atomicAdd(&lh[dst[e] >> BSHIFT], 1);
  __syncthreads();
  if (threadIdx.x < 128) {
    int v = lh[threadIdx.x];
    lbase[threadIdx.x] = v ? atomicAdd(&bcursor[threadIdx.x], v) : 0;
  }
  __syncthreads();
  for (int e = e0 + threadIdx.x; e < e1; e += 256) {
    int d = dst[e], b = d >> BSHIFT;
    int o = atomicAdd(&loff[b], 1);
    pairs[lbase[b] + o] = (unsigned int)src[e] | ((unsigned int)(d & 1023) << 17);
  }
}

// -- fused per-bucket: degree hist -> in-LDS scan (pad to 8) -> CSR scatter ----
static __global__ __launch_bounds__(1024) void k_bucket(const unsigned int* __restrict__ pairs,
                                                        const int* __restrict__ bcursor,
                                                        int* __restrict__ rowstart,
                                                        int* __restrict__ degi,
                                                        float* __restrict__ dinv,
                                                        int* __restrict__ csr_src) {
  __shared__ int lh[1024];
  __shared__ int tmp[1024];
  __shared__ int cur[1024];
  int t = threadIdx.x;
  int b = blockIdx.x, nb = b << BSHIFT;
  lh[t] = 0;
  __syncthreads();
  int p0 = b * PSLOT, p1 = bcursor[b];
  for (int p = p0 + t; p < p1; p += 1024)
    atomicAdd(&lh[pairs[p] >> 17], 1);
  __syncthreads();
  int node = nb + t;
  int raw = lh[t];
  int pd = (raw + 7) & ~7;          // pad to multiple of 8
  tmp[t] = pd;
  __syncthreads();
  for (int off = 1; off < 1024; off <<= 1) {
    int add = (t >= off) ? tmp[t - off] : 0;
    __syncthreads();
    tmp[t] += add;
    __syncthreads();
  }
  int ex = tmp[t] - pd;             // exclusive padded prefix within bucket
  int rs = b * CSLOT + ex;          // fixed-slot padded base
  if (node < NN) {
    rowstart[node] = rs;
    degi[node] = pd >> 3;           // niter (groups of 8)
    dinv[node] = rsqrtf((float)raw + 1.0f);
  }
  cur[t] = rs;
  __syncthreads();
  for (int p = p0 + t; p < p1; p += 1024) {
    unsigned int pk = pairs[p];
    int pos = atomicAdd(&cur[pk >> 17], 1);
    csr_src[pos] = (int)(pk & 0x1FFFFu);
  }
  __syncthreads();
  for (int q = raw; q < pd; ++q) csr_src[rs + q] = NN;  // sentinel fill
}

// -- GEMM 1 (MFMA): h = bf16(dinv * (x @ W1)), 16-row tile per wave ------------
static __global__ __launch_bounds__(256) void k_gemm1(const float* __restrict__ x,
                                                      const ushortT* __restrict__ W1T,
                                                      const float* __restrict__ dinv,
                                                      ushortT* __restrict__ h) {
  int wave = threadIdx.x >> 6, lane = threadIdx.x & 63;
  int tile = blockIdx.x * 4 + wave;
  if (tile >= NTILE) return;
  int m = lane & 15;
  int kb = (lane >> 4) * 8;
  int row = tile * 16 + m;
  const float* xr = x + (size_t)row * CIN;
  float4 a0l = *(const float4*)(xr + kb);
  float4 a0h = *(const float4*)(xr + kb + 4);
  float4 a1l = *(const float4*)(xr + kb + 32);
  float4 a1h = *(const float4*)(xr + kb + 36);
  bfrag A0 = pack8(a0l, a0h);
  bfrag A1 = pack8(a1l, a1h);
  int nl = lane & 15;
  ffrag z = {0.f, 0.f, 0.f, 0.f};
  bfrag B00 = *(const bfrag*)(W1T + (0 * 16 + nl) * CIN + kb);
  bfrag B01 = *(const bfrag*)(W1T + (0 * 16 + nl) * CIN + kb + 32);
  bfrag B10 = *(const bfrag*)(W1T + (1 * 16 + nl) * CIN + kb);
  bfrag B11 = *(const bfrag*)(W1T + (1 * 16 + nl) * CIN + kb + 32);
  bfrag B20 = *(const bfrag*)(W1T + (2 * 16 + nl) * CIN + kb);
  bfrag B21 = *(const bfrag*)(W1T + (2 * 16 + nl) * CIN + kb + 32);
  bfrag B30 = *(const bfrag*)(W1T + (3 * 16 + nl) * CIN + kb);
  bfrag B31 = *(const bfrag*)(W1T + (3 * 16 + nl) * CIN + kb + 32);
  ffrag c0 = __builtin_amdgcn_mfma_f32_16x16x32_bf16(A0, B00, z, 0, 0, 0);
  c0 = __builtin_amdgcn_mfma_f32_16x16x32_bf16(A1, B01, c0, 0, 0, 0);
  ffrag c1 = __builtin_amdgcn_mfma_f32_16x16x32_bf16(A0, B10, z, 0, 0, 0);
  c1 = __builtin_amdgcn_mfma_f32_16x16x32_bf16(A1, B11, c1, 0, 0, 0);
  ffrag c2 = __builtin_amdgcn_mfma_f32_16x16x32_bf16(A0, B20, z, 0, 0, 0);
  c2 = __builtin_amdgcn_mfma_f32_16x16x32_bf16(A1, B21, c2, 0, 0, 0);
  ffrag c3 = __builtin_amdgcn_mfma_f32_16x16x32_bf16(A0, B30, z, 0, 0, 0);
  c3 = __builtin_amdgcn_mfma_f32_16x16x32_bf16(A1, B31, c3, 0, 0, 0);
  int rbase = tile * 16 + (lane >> 4) * 4;
  float d0 = dinv[rbase + 0], d1 = dinv[rbase + 1], d2 = dinv[rbase + 2], d3 = dinv[rbase + 3];
  ushortT* hb = h + (size_t)rbase * CH + nl;
  hb[0 * CH + 0]  = f2bf(c0[0] * d0); hb[1 * CH + 0]  = f2bf(c0[1] * d1);
  hb[2 * CH + 0]  = f2bf(c0[2] * d2); hb[3 * CH + 0]  = f2bf(c0[3] * d3);
  hb[0 * CH + 16] = f2bf(c1[0] * d0); hb[1 * CH + 16] = f2bf(c1[1] * d1);
  hb[2 * CH + 16] = f2bf(c1[2] * d2); hb[3 * CH + 16] = f2bf(c1[3] * d3);
  hb[0 * CH + 32] = f2bf(c2[0] * d0); hb[1 * CH + 32] = f2bf(c2[1] * d1);
  hb[2 * CH + 32] = f2bf(c2[2] * d2); hb[3 * CH + 32] = f2bf(c2[3] * d3);
  hb[0 * CH + 48] = f2bf(c3[0] * d0); hb[1 * CH + 48] = f2bf(c3[1] * d1);
  hb[2 * CH + 48] = f2bf(c3[2] * d2); hb[3 * CH + 48] = f2bf(c3[3] * d3);
}

// -- layer-1 agg: uniform node/wave; padded tail-free 8-wide loop; bf16 out ----
static __global__ __launch_bounds__(256) void k_agg64(const ushortT* __restrict__ h,
                                                      const float* __restrict__ dinv,
                                                      const int* __restrict__ rowstart,
                                                      const int* __restrict__ degi,
                                                      const int* __restrict__ csr_src,
                                                      const float* __restrict__ b1,
                                                      ushortT* __restrict__ aggb) {
  int wave = threadIdx.x >> 6, lane = threadIdx.x & 63;
  int i = __builtin_amdgcn_readfirstlane(blockIdx.x * 4 + wave);  // uniform node
  float bias = b1[lane];
  float acc = bf2f(h[(size_t)i * CH + lane]);   // self-loop (h already dinv-scaled)
  int s0 = rowstart[i], niter = degi[i];        // scalar loads (uniform addr)
  for (int it = 0; it < niter; ++it) {
    int base = s0 + it * 8;
    int i0 = csr_src[base + 0];
    int i1 = csr_src[base + 1];
    int i2 = csr_src[base + 2];
    int i3 = csr_src[base + 3];
    int i4 = csr_src[base + 4];
    int i5 = csr_src[base + 5];
    int i6 = csr_src[base + 6];
    int i7 = csr_src[base + 7];
    float a0 = bf2f(h[(size_t)i0 * CH + lane]);
    float a1 = bf2f(h[(size_t)i1 * CH + lane]);
    float a2 = bf2f(h[(size_t)i2 * CH + lane]);
    float a3 = bf2f(h[(size_t)i3 * CH + lane]);
    float a4 = bf2f(h[(size_t)i4 * CH + lane]);
    float a5 = bf2f(h[(size_t)i5 * CH + lane]);
    float a6 = bf2f(h[(size_t)i6 * CH + lane]);
    float a7 = bf2f(h[(size_t)i7 * CH + lane]);
    acc += ((a0 + a1) + (a2 + a3)) + ((a4 + a5) + (a6 + a7));
  }
  float v = acc * dinv[i] + bias;
  aggb[(size_t)i * CH + lane] = f2bf(v > 0.0f ? v : 0.0f);
}

// -- GEMM 2 (MFMA): h2 = bf16(dinv * (aggRelu @ W2)) ---------------------------
static __global__ __launch_bounds__(256) void k_gemm2(const ushortT* __restrict__ aggb,
                                                      const ushortT* __restrict__ W2T,
                                                      const float* __restrict__ dinv,
                                                      ushortT* __restrict__ h2) {
  if (blockIdx.x == 0 && threadIdx.x < CO) h2[(size_t)NN * CO + threadIdx.x] = 0;  // h2 sentinel
  int wave = threadIdx.x >> 6, lane = threadIdx.x & 63;
  int tile = blockIdx.x * 4 + wave;
  if (tile >= NTILE) return;
  int m = lane & 15;
  int kb = (lane >> 4) * 8;
  int row = tile * 16 + m;
  bfrag A0 = *(const bfrag*)(aggb + (size_t)row * CH + kb);
  bfrag A1 = *(const bfrag*)(aggb + (size_t)row * CH + kb + 32);
  int nl = lane & 15;
  ffrag z = {0.f, 0.f, 0.f, 0.f};
  bfrag B00 = *(const bfrag*)(W2T + (0 * 16 + nl) * CH + kb);
  bfrag B01 = *(const bfrag*)(W2T + (0 * 16 + nl) * CH + kb + 32);
  bfrag B10 = *(const bfrag*)(W2T + (1 * 16 + nl) * CH + kb);
  bfrag B11 = *(const bfrag*)(W2T + (1 * 16 + nl) * CH + kb + 32);
  ffrag c0 = __builtin_amdgcn_mfma_f32_16x16x32_bf16(A0, B00, z, 0, 0, 0);
  c0 = __builtin_amdgcn_mfma_f32_16x16x32_bf16(A1, B01, c0, 0, 0, 0);
  ffrag c1 = __builtin_amdgcn_mfma_f32_16x16x32_bf16(A0, B10, z, 0, 0, 0);
  c1 = __builtin_amdgcn_mfma_f32_16x16x32_bf16(A1, B11, c1, 0, 0, 0);
  int rbase = tile * 16 + (lane >> 4) * 4;
  float d0 = dinv[rbase + 0], d1 = dinv[rbase + 1], d2 = dinv[rbase + 2], d3 = dinv[rbase + 3];
  ushortT* hb = h2 + (size_t)rbase * CO + nl;
  hb[0 * CO + 0]  = f2bf(c0[0] * d0); hb[1 * CO + 0]  = f2bf(c0[1] * d1);
  hb[2 * CO + 0]  = f2bf(c0[2] * d2); hb[3 * CO + 0]  = f2bf(c0[3] * d3);
  hb[0 * CO + 16] = f2bf(c1[0] * d0); hb[1 * CO + 16] = f2bf(c1[1] * d1);
  hb[2 * CO + 16] = f2bf(c1[2] * d2); hb[3 * CO + 16] = f2bf(c1[3] * d3);
}

// -- layer-2 agg: uniform node/wave; parity split; tail-free padded loop -------
static __global__ __launch_bounds__(256) void k_agg32pool(const ushortT* __restrict__ h2,
                                                          const float* __restrict__ dinv,
                                                          const int* __restrict__ rowstart,
                                                          const int* __restrict__ degi,
                                                          const int* __restrict__ csr_src,
                                                          const int* __restrict__ batch,
                                                          const float* __restrict__ b2,
                                                          float* __restrict__ sums) {
  __shared__ float vals[4][CO];
  __shared__ int gid[4];
  int wave = threadIdx.x >> 6, lane = threadIdx.x & 63;
  int g = lane >> 5;          // neighbor parity 0/1
  int j = lane & 31;          // channel
  int i = __builtin_amdgcn_readfirstlane(blockIdx.x * 4 + wave);  // uniform node
  int s0 = rowstart[i], niter = degi[i];  // scalar loads
  float acc = 0.0f;
  for (int it = 0; it < niter; ++it) {
    int base = s0 + it * 8;
    int i0 = csr_src[base + 0];
    int i1 = csr_src[base + 1];
    int i2 = csr_src[base + 2];
    int i3 = csr_src[base + 3];
    int i4 = csr_src[base + 4];
    int i5 = csr_src[base + 5];
    int i6 = csr_src[base + 6];
    int i7 = csr_src[base + 7];
    int sa = g ? i1 : i0;
    int sb = g ? i3 : i2;
    int sc = g ? i5 : i4;
    int sd = g ? i7 : i6;
    float a = bf2f(h2[(size_t)sa * CO + j]);
    float b = bf2f(h2[(size_t)sb * CO + j]);
    float c = bf2f(h2[(size_t)sc * CO + j]);
    float d = bf2f(h2[(size_t)sd * CO + j]);
    acc += (a + b) + (c + d);
  }
  acc += __shfl_xor(acc, 32);   // combine neighbor parities
  if (g == 0) {
    acc += bf2f(h2[(size_t)i * CO + j]);  // self-loop
    vals[wave][j] = acc * dinv[i] + b2[j];
    if (j == 0) gid[wave] = batch[i];
  }
  __syncthreads();
  if (threadIdx.x < 32) {
    int ch = threadIdx.x;
    float run = vals[0][ch];
    int gg = gid[0];
    for (int s = 1; s < 4; ++s) {
      if (gid[s] == gg) run += vals[s][ch];
      else { atomicAdd(&sums[gg * CO + ch], run); gg = gid[s]; run = vals[s][ch]; }
    }
    atomicAdd(&sums[gg * CO + ch], run);
  }
}

static __global__ void k_final(const float* __restrict__ sums, const float* __restrict__ counts,
                               float* __restrict__ out) {
  int t = blockIdx.x * 256 + threadIdx.x;
  if (t >= NG * CO) return;
  out[t] = sums[t] / fmaxf(counts[t >> 5], 1.0f);
}

extern "C" void kernel_launch(void* const* d_in, const int* in_sizes, int n_in,
                              void* d_out, int out_size, void* d_ws, size_t ws_size,
                              hipStream_t stream) {
  const float* x   = (const float*)d_in[0];
  const int* ei    = (const int*)d_in[1];   // [2, NE]: src = ei, dst = ei+NE
  const int* batch = (const int*)d_in[2];
  const float* W1  = (const float*)d_in[3];
  const float* b1  = (const float*)d_in[4];
  const float* W2  = (const float*)d_in[5];
  const float* b2  = (const float*)d_in[6];
  float* out = (float*)d_out;

  const int* src = ei;
  const int* dst = ei + NE;

  char* base = (char*)d_ws;
  size_t off = 0;
  auto allocB = [&](size_t nbytes) {
    void* p = (void*)(base + off);
    off += ((nbytes + 255) / 256) * 256;
    return p;
  };
  int* degi      = (int*)allocB(NN * 4);
  int* rowstart  = (int*)allocB(NN * 4);
  float* dinv    = (float*)allocB(NN * 4);
  int* bcursor   = (int*)allocB(128 * 4);
  ushortT* W1T   = (ushortT*)allocB(CIN * CH * 2);
  ushortT* W2T   = (ushortT*)allocB(CH * CO * 2);
  int* csr_src   = (int*)allocB((size_t)NBUCK * CSLOT * 4);     // 9.6 MB (padded)
  ushortT* hbuf  = (ushortT*)allocB((size_t)(NN + 1) * CH * 2); // h1 bf16 (+zero row); h2 reuses
  ushortT* aggb  = (ushortT*)allocB((size_t)(NN + 1) * CH * 2); // pairs (6.4 MB) then agg1 bf16
  float* sums    = (float*)allocB(NG * CO * 4);
  float* counts  = (float*)allocB(NG * 4);
  unsigned int* pairs = (unsigned int*)aggb;  // dead once k_bucket finishes

  dim3 B(256);
  // CSR build (fixed-slot buckets, fused scan+scatter, padded rows)
  k_zero<<<dim3(16), B, 0, stream>>>(sums, bcursor, batch, counts, W1, W1T, W2, W2T, hbuf);
  k_part<<<dim3(NBLKP), B, 0, stream>>>(src, dst, bcursor, pairs);
  k_bucket<<<dim3(NBUCK), dim3(1024), 0, stream>>>(pairs, bcursor, rowstart, degi, dinv, csr_src);
  // layer 1
  k_gemm1<<<dim3(GB), B, 0, stream>>>(x, W1T, dinv, hbuf);
  k_agg64<<<dim3(NN / 4), B, 0, stream>>>(hbuf, dinv, rowstart, degi, csr_src, b1, aggb);
  // layer 2
  k_gemm2<<<dim3(GB), B, 0, stream>>>(aggb, W2T, dinv, hbuf);
  k_agg32pool<<<dim3(NN / 4), B, 0, stream>>>(hbuf, dinv, rowstart, degi, csr_src, batch, b2, sums);
  // finalize
  k_final<<<dim3(16), B, 0, stream>>>(sums, counts, out);
}

// Round 23
// 136.660 us; speedup vs baseline: 1.9343x; 1.1754x over previous
//
#include <hip/hip_runtime.h>

#define NN 100000
#define NE 1250000
#define CIN 64
#define CH 64
#define CO 32
#define NG 128
#define NBUCK 98                     // buckets of 1024 nodes: dst>>10 in [0,97]
#define BSHIFT 10
#define EPB 2048                     // edges per partition block
#define NBLKP ((NE + EPB - 1) / EPB) // 611
#define PSLOT 16384                  // pairs slots per bucket (max count ~13.4K)
#define CSLOT 24576                  // csr slots per bucket (count + pad <= 20.6K)
#define NTILE (NN / 16)              // 6250 MFMA row-tiles
#define GB ((NTILE + 3) / 4)         // 1563 blocks, 4 waves each

typedef unsigned short ushortT;
typedef __attribute__((ext_vector_type(8))) short bfrag;   // 8 bf16 (4 VGPR)
typedef __attribute__((ext_vector_type(4))) float ffrag;   // 4 fp32 acc

static __device__ inline ushortT f2bf(float v) {
  unsigned int u = __float_as_uint(v);
  u += 0x7FFFu + ((u >> 16) & 1u);   // round-to-nearest-even
  return (ushortT)(u >> 16);
}
static __device__ inline float bf2f(ushortT s) {
  return __uint_as_float(((unsigned int)s) << 16);
}
static __device__ inline bfrag pack8(float4 lo, float4 hi) {
  bfrag r;
  r[0] = (short)f2bf(lo.x); r[1] = (short)f2bf(lo.y);
  r[2] = (short)f2bf(lo.z); r[3] = (short)f2bf(lo.w);
  r[4] = (short)f2bf(hi.x); r[5] = (short)f2bf(hi.y);
  r[6] = (short)f2bf(hi.z); r[7] = (short)f2bf(hi.w);
  return r;
}

// -- init: sums, bucket cursors, counts, bf16-transposed weights, h1 sentinel --
static __global__ void k_zero(float* __restrict__ sums, int* __restrict__ bcursor,
                              const int* __restrict__ batch, float* __restrict__ counts,
                              const float* __restrict__ W1, ushortT* __restrict__ W1T,
                              const float* __restrict__ W2, ushortT* __restrict__ W2T,
                              ushortT* __restrict__ h) {
  int i = blockIdx.x * 256 + threadIdx.x;  // grid 16*256 = 4096
  if (i < NG * CO) sums[i] = 0.0f;
  if (i < 128) bcursor[i] = i * PSLOT;
  if (i < CH) h[(size_t)NN * CH + i] = 0;                    // h1 sentinel row
  if (i < CIN * CH) W1T[i] = f2bf(W1[(i & 63) * CH + (i >> 6)]);   // W1T[n][k]
  if (i < CH * CO) W2T[i] = f2bf(W2[(i & 63) * CO + (i >> 6)]);    // W2T[n][k]
  if (blockIdx.x == 0 && threadIdx.x < NG) {
    int g = threadIdx.x;
    int lo = 0, hi = NN;
    while (lo < hi) { int m = (lo + hi) >> 1; if (batch[m] < g) lo = m + 1; else hi = m; }
    int lb = lo;
    lo = 0; hi = NN;
    while (lo < hi) { int m = (lo + hi) >> 1; if (batch[m] <= g) lo = m + 1; else hi = m; }
    counts[g] = (float)(lo - lb);
  }
}

// -- partition edges into fixed-slot bucket runs: pk = src | (d&1023)<<17 ------
static __global__ __launch_bounds__(256) void k_part(const int* __restrict__ src,
                                                     const int* __restrict__ dst,
                                                     int* __restrict__ bcursor,
                                                     unsigned int* __restrict__ pairs) {
  __shared__ int lh[128], lbase[128], loff[128];
  if (threadIdx.x < 128) { lh[threadIdx.x] = 0; loff[threadIdx.x] = 0; }
  __syncthreads();
  int e0 = blockIdx.x * EPB, e1 = min(e0 + EPB, NE);
  for (int e = e0 + threadIdx.x; e < e1; e += 256)
    atomicAdd(&lh[dst[e] >> BSHIFT], 1);
  __syncthreads();
  if (threadIdx.x < 128) {
    int v = lh[threadIdx.x];
    lbase[threadIdx.x] = v ? atomicAdd(&bcursor[threadIdx.x], v) : 0;
  }
  __syncthreads();
  for (int e = e0 + threadIdx.x; e < e1; e += 256) {
    int d = dst[e], b = d >> BSHIFT;
    int o = atomicAdd(&loff[b], 1);
    pairs[lbase[b] + o] = (unsigned int)src[e] | ((unsigned int)(d & 1023) << 17);
  }
}

// -- fused per-bucket: degree hist -> in-LDS scan (pad to 8) -> CSR scatter ----
static __global__ __launch_bounds__(1024) void k_bucket(const unsigned int* __restrict__ pairs,
                                                        const int* __restrict__ bcursor,
                                                        int* __restrict__ rowstart,
                                                        int* __restrict__ degi,
                                                        float* __restrict__ dinv,
                                                        int* __restrict__ csr_src) {
  __shared__ int lh[1024];
  __shared__ int tmp[1024];
  __shared__ int cur[1024];
  int t = threadIdx.x;
  int b = blockIdx.x, nb = b << BSHIFT;
  lh[t] = 0;
  __syncthreads();
  int p0 = b * PSLOT, p1 = bcursor[b];
  for (int p = p0 + t; p < p1; p += 1024)
    atomicAdd(&lh[pairs[p] >> 17], 1);
  __syncthreads();
  int node = nb + t;
  int raw = lh[t];
  int pd = (raw + 7) & ~7;          // pad to multiple of 8
  tmp[t] = pd;
  __syncthreads();
  for (int off = 1; off < 1024; off <<= 1) {
    int add = (t >= off) ? tmp[t - off] : 0;
    __syncthreads();
    tmp[t] += add;
    __syncthreads();
  }
  int ex = tmp[t] - pd;             // exclusive padded prefix within bucket
  int rs = b * CSLOT + ex;          // fixed-slot padded base
  if (node < NN) {
    rowstart[node] = rs;
    degi[node] = pd >> 3;           // niter (groups of 8)
    dinv[node] = rsqrtf((float)raw + 1.0f);
  }
  cur[t] = rs;
  __syncthreads();
  for (int p = p0 + t; p < p1; p += 1024) {
    unsigned int pk = pairs[p];
    int pos = atomicAdd(&cur[pk >> 17], 1);
    csr_src[pos] = (int)(pk & 0x1FFFFu);
  }
  __syncthreads();
  for (int q = raw; q < pd; ++q) csr_src[rs + q] = NN;  // sentinel fill
}

// -- GEMM 1 (MFMA): h = bf16(dinv * (x @ W1)), 16-row tile per wave ------------
static __global__ __launch_bounds__(256) void k_gemm1(const float* __restrict__ x,
                                                      const ushortT* __restrict__ W1T,
                                                      const float* __restrict__ dinv,
                                                      ushortT* __restrict__ h) {
  int wave = threadIdx.x >> 6, lane = threadIdx.x & 63;
  int tile = blockIdx.x * 4 + wave;
  if (tile >= NTILE) return;
  int m = lane & 15;
  int kb = (lane >> 4) * 8;
  int row = tile * 16 + m;
  const float* xr = x + (size_t)row * CIN;
  float4 a0l = *(const float4*)(xr + kb);
  float4 a0h = *(const float4*)(xr + kb + 4);
  float4 a1l = *(const float4*)(xr + kb + 32);
  float4 a1h = *(const float4*)(xr + kb + 36);
  bfrag A0 = pack8(a0l, a0h);
  bfrag A1 = pack8(a1l, a1h);
  int nl = lane & 15;
  ffrag z = {0.f, 0.f, 0.f, 0.f};
  bfrag B00 = *(const bfrag*)(W1T + (0 * 16 + nl) * CIN + kb);
  bfrag B01 = *(const bfrag*)(W1T + (0 * 16 + nl) * CIN + kb + 32);
  bfrag B10 = *(const bfrag*)(W1T + (1 * 16 + nl) * CIN + kb);
  bfrag B11 = *(const bfrag*)(W1T + (1 * 16 + nl) * CIN + kb + 32);
  bfrag B20 = *(const bfrag*)(W1T + (2 * 16 + nl) * CIN + kb);
  bfrag B21 = *(const bfrag*)(W1T + (2 * 16 + nl) * CIN + kb + 32);
  bfrag B30 = *(const bfrag*)(W1T + (3 * 16 + nl) * CIN + kb);
  bfrag B31 = *(const bfrag*)(W1T + (3 * 16 + nl) * CIN + kb + 32);
  ffrag c0 = __builtin_amdgcn_mfma_f32_16x16x32_bf16(A0, B00, z, 0, 0, 0);
  c0 = __builtin_amdgcn_mfma_f32_16x16x32_bf16(A1, B01, c0, 0, 0, 0);
  ffrag c1 = __builtin_amdgcn_mfma_f32_16x16x32_bf16(A0, B10, z, 0, 0, 0);
  c1 = __builtin_amdgcn_mfma_f32_16x16x32_bf16(A1, B11, c1, 0, 0, 0);
  ffrag c2 = __builtin_amdgcn_mfma_f32_16x16x32_bf16(A0, B20, z, 0, 0, 0);
  c2 = __builtin_amdgcn_mfma_f32_16x16x32_bf16(A1, B21, c2, 0, 0, 0);
  ffrag c3 = __builtin_amdgcn_mfma_f32_16x16x32_bf16(A0, B30, z, 0, 0, 0);
  c3 = __builtin_amdgcn_mfma_f32_16x16x32_bf16(A1, B31, c3, 0, 0, 0);
  int rbase = tile * 16 + (lane >> 4) * 4;
  float d0 = dinv[rbase + 0], d1 = dinv[rbase + 1], d2 = dinv[rbase + 2], d3 = dinv[rbase + 3];
  ushortT* hb = h + (size_t)rbase * CH + nl;
  hb[0 * CH + 0]  = f2bf(c0[0] * d0); hb[1 * CH + 0]  = f2bf(c0[1] * d1);
  hb[2 * CH + 0]  = f2bf(c0[2] * d2); hb[3 * CH + 0]  = f2bf(c0[3] * d3);
  hb[0 * CH + 16] = f2bf(c1[0] * d0); hb[1 * CH + 16] = f2bf(c1[1] * d1);
  hb[2 * CH + 16] = f2bf(c1[2] * d2); hb[3 * CH + 16] = f2bf(c1[3] * d3);
  hb[0 * CH + 32] = f2bf(c2[0] * d0); hb[1 * CH + 32] = f2bf(c2[1] * d1);
  hb[2 * CH + 32] = f2bf(c2[2] * d2); hb[3 * CH + 32] = f2bf(c2[3] * d3);
  hb[0 * CH + 48] = f2bf(c3[0] * d0); hb[1 * CH + 48] = f2bf(c3[1] * d1);
  hb[2 * CH + 48] = f2bf(c3[2] * d2); hb[3 * CH + 48] = f2bf(c3[3] * d3);
}

// -- layer-1 agg: TWO nodes per wave (16 gathers in flight); bf16 out ----------
static __global__ __launch_bounds__(256) void k_agg64(const ushortT* __restrict__ h,
                                                      const float* __restrict__ dinv,
                                                      const int* __restrict__ rowstart,
                                                      const int* __restrict__ degi,
                                                      const int* __restrict__ csr_src,
                                                      const float* __restrict__ b1,
                                                      ushortT* __restrict__ aggb) {
  int wave = threadIdx.x >> 6, lane = threadIdx.x & 63;
  int iA = __builtin_amdgcn_readfirstlane(blockIdx.x * 8 + wave * 2);
  int iB = iA + 1;
  float bias = b1[lane];
  float accA = bf2f(h[(size_t)iA * CH + lane]);   // self-loops (h dinv-scaled)
  float accB = bf2f(h[(size_t)iB * CH + lane]);
  int s0A = rowstart[iA], nA = degi[iA];          // scalar loads
  int s0B = rowstart[iB], nB = degi[iB];
  int nmax = max(nA, nB);
  for (int it = 0; it < nmax; ++it) {
    int itA = nA ? min(it, nA - 1) : 0;
    int itB = nB ? min(it, nB - 1) : 0;
    int baseA = s0A + itA * 8;
    int baseB = s0B + itB * 8;
    float mA = it < nA ? 1.0f : 0.0f;
    float mB = it < nB ? 1.0f : 0.0f;
    int a0 = csr_src[baseA + 0], a1 = csr_src[baseA + 1];
    int a2 = csr_src[baseA + 2], a3 = csr_src[baseA + 3];
    int a4 = csr_src[baseA + 4], a5 = csr_src[baseA + 5];
    int a6 = csr_src[baseA + 6], a7 = csr_src[baseA + 7];
    int b0 = csr_src[baseB + 0], b1i = csr_src[baseB + 1];
    int b2i = csr_src[baseB + 2], b3 = csr_src[baseB + 3];
    int b4 = csr_src[baseB + 4], b5 = csr_src[baseB + 5];
    int b6 = csr_src[baseB + 6], b7 = csr_src[baseB + 7];
    float fa0 = bf2f(h[(size_t)a0 * CH + lane]);
    float fa1 = bf2f(h[(size_t)a1 * CH + lane]);
    float fa2 = bf2f(h[(size_t)a2 * CH + lane]);
    float fa3 = bf2f(h[(size_t)a3 * CH + lane]);
    float fa4 = bf2f(h[(size_t)a4 * CH + lane]);
    float fa5 = bf2f(h[(size_t)a5 * CH + lane]);
    float fa6 = bf2f(h[(size_t)a6 * CH + lane]);
    float fa7 = bf2f(h[(size_t)a7 * CH + lane]);
    float fb0 = bf2f(h[(size_t)b0 * CH + lane]);
    float fb1 = bf2f(h[(size_t)b1i * CH + lane]);
    float fb2 = bf2f(h[(size_t)b2i * CH + lane]);
    float fb3 = bf2f(h[(size_t)b3 * CH + lane]);
    float fb4 = bf2f(h[(size_t)b4 * CH + lane]);
    float fb5 = bf2f(h[(size_t)b5 * CH + lane]);
    float fb6 = bf2f(h[(size_t)b6 * CH + lane]);
    float fb7 = bf2f(h[(size_t)b7 * CH + lane]);
    accA += mA * (((fa0 + fa1) + (fa2 + fa3)) + ((fa4 + fa5) + (fa6 + fa7)));
    accB += mB * (((fb0 + fb1) + (fb2 + fb3)) + ((fb4 + fb5) + (fb6 + fb7)));
  }
  float vA = accA * dinv[iA] + bias;
  float vB = accB * dinv[iB] + bias;
  aggb[(size_t)iA * CH + lane] = f2bf(vA > 0.0f ? vA : 0.0f);
  aggb[(size_t)iB * CH + lane] = f2bf(vB > 0.0f ? vB : 0.0f);
}

// -- GEMM 2 (MFMA): h2 = bf16(dinv * (aggRelu @ W2)) ---------------------------
static __global__ __launch_bounds__(256) void k_gemm2(const ushortT* __restrict__ aggb,
                                                      const ushortT* __restrict__ W2T,
                                                      const float* __restrict__ dinv,
                                                      ushortT* __restrict__ h2) {
  if (blockIdx.x == 0 && threadIdx.x < CO) h2[(size_t)NN * CO + threadIdx.x] = 0;  // h2 sentinel
  int wave = threadIdx.x >> 6, lane = threadIdx.x & 63;
  int tile = blockIdx.x * 4 + wave;
  if (tile >= NTILE) return;
  int m = lane & 15;
  int kb = (lane >> 4) * 8;
  int row = tile * 16 + m;
  bfrag A0 = *(const bfrag*)(aggb + (size_t)row * CH + kb);
  bfrag A1 = *(const bfrag*)(aggb + (size_t)row * CH + kb + 32);
  int nl = lane & 15;
  ffrag z = {0.f, 0.f, 0.f, 0.f};
  bfrag B00 = *(const bfrag*)(W2T + (0 * 16 + nl) * CH + kb);
  bfrag B01 = *(const bfrag*)(W2T + (0 * 16 + nl) * CH + kb + 32);
  bfrag B10 = *(const bfrag*)(W2T + (1 * 16 + nl) * CH + kb);
  bfrag B11 = *(const bfrag*)(W2T + (1 * 16 + nl) * CH + kb + 32);
  ffrag c0 = __builtin_amdgcn_mfma_f32_16x16x32_bf16(A0, B00, z, 0, 0, 0);
  c0 = __builtin_amdgcn_mfma_f32_16x16x32_bf16(A1, B01, c0, 0, 0, 0);
  ffrag c1 = __builtin_amdgcn_mfma_f32_16x16x32_bf16(A0, B10, z, 0, 0, 0);
  c1 = __builtin_amdgcn_mfma_f32_16x16x32_bf16(A1, B11, c1, 0, 0, 0);
  int rbase = tile * 16 + (lane >> 4) * 4;
  float d0 = dinv[rbase + 0], d1 = dinv[rbase + 1], d2 = dinv[rbase + 2], d3 = dinv[rbase + 3];
  ushortT* hb = h2 + (size_t)rbase * CO + nl;
  hb[0 * CO + 0]  = f2bf(c0[0] * d0); hb[1 * CO + 0]  = f2bf(c0[1] * d1);
  hb[2 * CO + 0]  = f2bf(c0[2] * d2); hb[3 * CO + 0]  = f2bf(c0[3] * d3);
  hb[0 * CO + 16] = f2bf(c1[0] * d0); hb[1 * CO + 16] = f2bf(c1[1] * d1);
  hb[2 * CO + 16] = f2bf(c1[2] * d2); hb[3 * CO + 16] = f2bf(c1[3] * d3);
}

// -- layer-2 agg: TWO nodes per wave; parity split per node; mean-pool ---------
static __global__ __launch_bounds__(256) void k_agg32pool(const ushortT* __restrict__ h2,
                                                          const float* __restrict__ dinv,
                                                          const int* __restrict__ rowstart,
                                                          const int* __restrict__ degi,
                                                          const int* __restrict__ csr_src,
                                                          const int* __restrict__ batch,
                                                          const float* __restrict__ b2,
                                                          float* __restrict__ sums) {
  __shared__ float vals[8][CO];
  __shared__ int gid[8];
  int wave = threadIdx.x >> 6, lane = threadIdx.x & 63;
  int g = lane >> 5;          // neighbor parity 0/1
  int j = lane & 31;          // channel
  int iA = __builtin_amdgcn_readfirstlane(blockIdx.x * 8 + wave * 2);
  int iB = iA + 1;
  int s0A = rowstart[iA], nA = degi[iA];
  int s0B = rowstart[iB], nB = degi[iB];
  float accA = 0.0f, accB = 0.0f;
  int nmax = max(nA, nB);
  for (int it = 0; it < nmax; ++it) {
    int itA = nA ? min(it, nA - 1) : 0;
    int itB = nB ? min(it, nB - 1) : 0;
    int baseA = s0A + itA * 8;
    int baseB = s0B + itB * 8;
    float mA = it < nA ? 1.0f : 0.0f;
    float mB = it < nB ? 1.0f : 0.0f;
    int a0 = csr_src[baseA + 0], a1 = csr_src[baseA + 1];
    int a2 = csr_src[baseA + 2], a3 = csr_src[baseA + 3];
    int a4 = csr_src[baseA + 4], a5 = csr_src[baseA + 5];
    int a6 = csr_src[baseA + 6], a7 = csr_src[baseA + 7];
    int b0 = csr_src[baseB + 0], b1i = csr_src[baseB + 1];
    int b2i = csr_src[baseB + 2], b3 = csr_src[baseB + 3];
    int b4 = csr_src[baseB + 4], b5 = csr_src[baseB + 5];
    int b6 = csr_src[baseB + 6], b7 = csr_src[baseB + 7];
    int saA = g ? a1 : a0;
    int sbA = g ? a3 : a2;
    int scA = g ? a5 : a4;
    int sdA = g ? a7 : a6;
    int saB = g ? b1i : b0;
    int sbB = g ? b3 : b2i;
    int scB = g ? b5 : b4;
    int sdB = g ? b7 : b6;
    float xa = bf2f(h2[(size_t)saA * CO + j]);
    float xb = bf2f(h2[(size_t)sbA * CO + j]);
    float xc = bf2f(h2[(size_t)scA * CO + j]);
    float xd = bf2f(h2[(size_t)sdA * CO + j]);
    float ya = bf2f(h2[(size_t)saB * CO + j]);
    float yb = bf2f(h2[(size_t)sbB * CO + j]);
    float yc = bf2f(h2[(size_t)scB * CO + j]);
    float yd = bf2f(h2[(size_t)sdB * CO + j]);
    accA += mA * ((xa + xb) + (xc + xd));
    accB += mB * ((ya + yb) + (yc + yd));
  }
  accA += __shfl_xor(accA, 32);   // combine neighbor parities
  accB += __shfl_xor(accB, 32);
  if (g == 0) {
    accA += bf2f(h2[(size_t)iA * CO + j]);  // self-loops
    accB += bf2f(h2[(size_t)iB * CO + j]);
    vals[wave * 2 + 0][j] = accA * dinv[iA] + b2[j];
    vals[wave * 2 + 1][j] = accB * dinv[iB] + b2[j];
    if (j == 0) { gid[wave * 2 + 0] = batch[iA]; gid[wave * 2 + 1] = batch[iB]; }
  }
  __syncthreads();
  if (threadIdx.x < 32) {
    int ch = threadIdx.x;
    float run = vals[0][ch];
    int gg = gid[0];
    for (int s = 1; s < 8; ++s) {
      if (gid[s] == gg) run += vals[s][ch];
      else { atomicAdd(&sums[gg * CO + ch], run); gg = gid[s]; run = vals[s][ch]; }
    }
    atomicAdd(&sums[gg * CO + ch], run);
  }
}

static __global__ void k_final(const float* __restrict__ sums, const float* __restrict__ counts,
                               float* __restrict__ out) {
  int t = blockIdx.x * 256 + threadIdx.x;
  if (t >= NG * CO) return;
  out[t] = sums[t] / fmaxf(counts[t >> 5], 1.0f);
}

extern "C" void kernel_launch(void* const* d_in, const int* in_sizes, int n_in,
                              void* d_out, int out_size, void* d_ws, size_t ws_size,
                              hipStream_t stream) {
  const float* x   = (const float*)d_in[0];
  const int* ei    = (const int*)d_in[1];   // [2, NE]: src = ei, dst = ei+NE
  const int* batch = (const int*)d_in[2];
  const float* W1  = (const float*)d_in[3];
  const float* b1  = (const float*)d_in[4];
  const float* W2  = (const float*)d_in[5];
  const float* b2  = (const float*)d_in[6];
  float* out = (float*)d_out;

  const int* src = ei;
  const int* dst = ei + NE;

  char* base = (char*)d_ws;
  size_t off = 0;
  auto allocB = [&](size_t nbytes) {
    void* p = (void*)(base + off);
    off += ((nbytes + 255) / 256) * 256;
    return p;
  };
  int* degi      = (int*)allocB(NN * 4);
  int* rowstart  = (int*)allocB(NN * 4);
  float* dinv    = (float*)allocB(NN * 4);
  int* bcursor   = (int*)allocB(128 * 4);
  ushortT* W1T   = (ushortT*)allocB(CIN * CH * 2);
  ushortT* W2T   = (ushortT*)allocB(CH * CO * 2);
  int* csr_src   = (int*)allocB((size_t)NBUCK * CSLOT * 4);     // 9.6 MB (padded)
  ushortT* hbuf  = (ushortT*)allocB((size_t)(NN + 1) * CH * 2); // h1 bf16 (+zero row); h2 reuses
  ushortT* aggb  = (ushortT*)allocB((size_t)(NN + 1) * CH * 2); // pairs (6.4 MB) then agg1 bf16
  float* sums    = (float*)allocB(NG * CO * 4);
  float* counts  = (float*)allocB(NG * 4);
  unsigned int* pairs = (unsigned int*)aggb;  // dead once k_bucket finishes

  dim3 B(256);
  // CSR build (fixed-slot buckets, fused scan+scatter, padded rows)
  k_zero<<<dim3(16), B, 0, stream>>>(sums, bcursor, batch, counts, W1, W1T, W2, W2T, hbuf);
  k_part<<<dim3(NBLKP), B, 0, stream>>>(src, dst, bcursor, pairs);
  k_bucket<<<dim3(NBUCK), dim3(1024), 0, stream>>>(pairs, bcursor, rowstart, degi, dinv, csr_src);
  // layer 1
  k_gemm1<<<dim3(GB), B, 0, stream>>>(x, W1T, dinv, hbuf);
  k_agg64<<<dim3(NN / 8), B, 0, stream>>>(hbuf, dinv, rowstart, degi, csr_src, b1, aggb);
  // layer 2
  k_gemm2<<<dim3(GB), B, 0, stream>>>(aggb, W2T, dinv, hbuf);
  k_agg32pool<<<dim3(NN / 8), B, 0, stream>>>(hbuf, dinv, rowstart, degi, csr_src, batch, b2, sums);
  // finalize
  k_final<<<dim3(16), B, 0, stream>>>(sums, counts, out);
}

// Round 24
// 131.741 us; speedup vs baseline: 2.0065x; 1.0373x over previous
//
#include <hip/hip_runtime.h>

#define NN 100000
#define NE 1250000
#define CIN 64
#define CH 64
#define CO 32
#define NG 128
#define NBUCK 98                     // buckets of 1024 nodes: dst>>10 in [0,97]
#define BSHIFT 10
#define EPB 2048                     // edges per partition block
#define NBLKP ((NE + EPB - 1) / EPB) // 611
#define PSLOT 16384                  // pairs slots per bucket (max count ~13.4K)
#define CSLOT 24576                  // csr slots per bucket (count + pad <= 20.6K)
#define NTILE (NN / 16)              // 6250 MFMA row-tiles
#define GB ((NTILE + 3) / 4)         // 1563 blocks, 4 waves each

typedef unsigned short ushortT;
typedef __attribute__((ext_vector_type(8))) short bfrag;   // 8 bf16 (4 VGPR)
typedef __attribute__((ext_vector_type(4))) float ffrag;   // 4 fp32 acc

static __device__ inline ushortT f2bf(float v) {
  unsigned int u = __float_as_uint(v);
  u += 0x7FFFu + ((u >> 16) & 1u);   // round-to-nearest-even
  return (ushortT)(u >> 16);
}
static __device__ inline float bf2f(ushortT s) {
  return __uint_as_float(((unsigned int)s) << 16);
}
static __device__ inline bfrag pack8(float4 lo, float4 hi) {
  bfrag r;
  r[0] = (short)f2bf(lo.x); r[1] = (short)f2bf(lo.y);
  r[2] = (short)f2bf(lo.z); r[3] = (short)f2bf(lo.w);
  r[4] = (short)f2bf(hi.x); r[5] = (short)f2bf(hi.y);
  r[6] = (short)f2bf(hi.z); r[7] = (short)f2bf(hi.w);
  return r;
}

// -- init: sums, bucket cursors, counts, bf16-transposed weights, h1 sentinel --
static __global__ void k_zero(float* __restrict__ sums, int* __restrict__ bcursor,
                              const int* __restrict__ batch, float* __restrict__ counts,
                              const float* __restrict__ W1, ushortT* __restrict__ W1T,
                              const float* __restrict__ W2, ushortT* __restrict__ W2T,
                              ushortT* __restrict__ h) {
  int i = blockIdx.x * 256 + threadIdx.x;  // grid 16*256 = 4096
  if (i < NG * CO) sums[i] = 0.0f;
  if (i < 128) bcursor[i] = i * PSLOT;
  if (i < CH) h[(size_t)NN * CH + i] = 0;                    // h1 sentinel row
  if (i < CIN * CH) W1T[i] = f2bf(W1[(i & 63) * CH + (i >> 6)]);   // W1T[n][k]
  if (i < CH * CO) W2T[i] = f2bf(W2[(i & 63) * CO + (i >> 6)]);    // W2T[n][k]
  if (blockIdx.x == 0 && threadIdx.x < NG) {
    int g = threadIdx.x;
    int lo = 0, hi = NN;
    while (lo < hi) { int m = (lo + hi) >> 1; if (batch[m] < g) lo = m + 1; else hi = m; }
    int lb = lo;
    lo = 0; hi = NN;
    while (lo < hi) { int m = (lo + hi) >> 1; if (batch[m] <= g) lo = m + 1; else hi = m; }
    counts[g] = (float)(lo - lb);
  }
}

// -- partition edges into fixed-slot bucket runs: pk = src | (d&1023)<<17 ------
static __global__ __launch_bounds__(256) void k_part(const int* __restrict__ src,
                                                     const int* __restrict__ dst,
                                                     int* __restrict__ bcursor,
                                                     unsigned int* __restrict__ pairs) {
  __shared__ int lh[128], lbase[128], loff[128];
  if (threadIdx.x < 128) { lh[threadIdx.x] = 0; loff[threadIdx.x] = 0; }
  __syncthreads();
  int e0 = blockIdx.x * EPB, e1 = min(e0 + EPB, NE);
  for (int e = e0 + threadIdx.x; e < e1; e += 256)
    atomicAdd(&lh[dst[e] >> BSHIFT], 1);
  __syncthreads();
  if (threadIdx.x < 128) {
    int v = lh[threadIdx.x];
    lbase[threadIdx.x] = v ? atomicAdd(&bcursor[threadIdx.x], v) : 0;
  }
  __syncthreads();
  for (int e = e0 + threadIdx.x; e < e1; e += 256) {
    int d = dst[e], b = d >> BSHIFT;
    int o = atomicAdd(&loff[b], 1);
    pairs[lbase[b] + o] = (unsigned int)src[e] | ((unsigned int)(d & 1023) << 17);
  }
}

// -- fused per-bucket: degree hist -> in-LDS scan (pad to 8) -> CSR scatter ----
static __global__ __launch_bounds__(1024) void k_bucket(const unsigned int* __restrict__ pairs,
                                                        const int* __restrict__ bcursor,
                                                        int* __restrict__ rowstart,
                                                        int* __restrict__ degi,
                                                        float* __restrict__ dinv,
                                                        int* __restrict__ csr_src) {
  __shared__ int lh[1024];
  __shared__ int tmp[1024];
  __shared__ int cur[1024];
  int t = threadIdx.x;
  int b = blockIdx.x, nb = b << BSHIFT;
  lh[t] = 0;
  __syncthreads();
  int p0 = b * PSLOT, p1 = bcursor[b];
  for (int p = p0 + t; p < p1; p += 1024)
    atomicAdd(&lh[pairs[p] >> 17], 1);
  __syncthreads();
  int node = nb + t;
  int raw = lh[t];
  int pd = (raw + 7) & ~7;          // pad to multiple of 8
  tmp[t] = pd;
  __syncthreads();
  for (int off = 1; off < 1024; off <<= 1) {
    int add = (t >= off) ? tmp[t - off] : 0;
    __syncthreads();
    tmp[t] += add;
    __syncthreads();
  }
  int ex = tmp[t] - pd;             // exclusive padded prefix within bucket
  int rs = b * CSLOT + ex;          // fixed-slot padded base
  if (node < NN) {
    rowstart[node] = rs;
    degi[node] = pd >> 3;           // niter (groups of 8)
    dinv[node] = rsqrtf((float)raw + 1.0f);
  }
  cur[t] = rs;
  __syncthreads();
  for (int p = p0 + t; p < p1; p += 1024) {
    unsigned int pk = pairs[p];
    int pos = atomicAdd(&cur[pk >> 17], 1);
    csr_src[pos] = (int)(pk & 0x1FFFFu);
  }
  __syncthreads();
  for (int q = raw; q < pd; ++q) csr_src[rs + q] = NN;  // sentinel fill
}

// -- GEMM 1 (MFMA): h = bf16(dinv * (x @ W1)), 16-row tile per wave ------------
static __global__ __launch_bounds__(256) void k_gemm1(const float* __restrict__ x,
                                                      const ushortT* __restrict__ W1T,
                                                      const float* __restrict__ dinv,
                                                      ushortT* __restrict__ h) {
  int wave = threadIdx.x >> 6, lane = threadIdx.x & 63;
  int tile = blockIdx.x * 4 + wave;
  if (tile >= NTILE) return;
  int m = lane & 15;
  int kb = (lane >> 4) * 8;
  int row = tile * 16 + m;
  const float* xr = x + (size_t)row * CIN;
  float4 a0l = *(const float4*)(xr + kb);
  float4 a0h = *(const float4*)(xr + kb + 4);
  float4 a1l = *(const float4*)(xr + kb + 32);
  float4 a1h = *(const float4*)(xr + kb + 36);
  bfrag A0 = pack8(a0l, a0h);
  bfrag A1 = pack8(a1l, a1h);
  int nl = lane & 15;
  ffrag z = {0.f, 0.f, 0.f, 0.f};
  bfrag B00 = *(const bfrag*)(W1T + (0 * 16 + nl) * CIN + kb);
  bfrag B01 = *(const bfrag*)(W1T + (0 * 16 + nl) * CIN + kb + 32);
  bfrag B10 = *(const bfrag*)(W1T + (1 * 16 + nl) * CIN + kb);
  bfrag B11 = *(const bfrag*)(W1T + (1 * 16 + nl) * CIN + kb + 32);
  bfrag B20 = *(const bfrag*)(W1T + (2 * 16 + nl) * CIN + kb);
  bfrag B21 = *(const bfrag*)(W1T + (2 * 16 + nl) * CIN + kb + 32);
  bfrag B30 = *(const bfrag*)(W1T + (3 * 16 + nl) * CIN + kb);
  bfrag B31 = *(const bfrag*)(W1T + (3 * 16 + nl) * CIN + kb + 32);
  ffrag c0 = __builtin_amdgcn_mfma_f32_16x16x32_bf16(A0, B00, z, 0, 0, 0);
  c0 = __builtin_amdgcn_mfma_f32_16x16x32_bf16(A1, B01, c0, 0, 0, 0);
  ffrag c1 = __builtin_amdgcn_mfma_f32_16x16x32_bf16(A0, B10, z, 0, 0, 0);
  c1 = __builtin_amdgcn_mfma_f32_16x16x32_bf16(A1, B11, c1, 0, 0, 0);
  ffrag c2 = __builtin_amdgcn_mfma_f32_16x16x32_bf16(A0, B20, z, 0, 0, 0);
  c2 = __builtin_amdgcn_mfma_f32_16x16x32_bf16(A1, B21, c2, 0, 0, 0);
  ffrag c3 = __builtin_amdgcn_mfma_f32_16x16x32_bf16(A0, B30, z, 0, 0, 0);
  c3 = __builtin_amdgcn_mfma_f32_16x16x32_bf16(A1, B31, c3, 0, 0, 0);
  int rbase = tile * 16 + (lane >> 4) * 4;
  float d0 = dinv[rbase + 0], d1 = dinv[rbase + 1], d2 = dinv[rbase + 2], d3 = dinv[rbase + 3];
  ushortT* hb = h + (size_t)rbase * CH + nl;
  hb[0 * CH + 0]  = f2bf(c0[0] * d0); hb[1 * CH + 0]  = f2bf(c0[1] * d1);
  hb[2 * CH + 0]  = f2bf(c0[2] * d2); hb[3 * CH + 0]  = f2bf(c0[3] * d3);
  hb[0 * CH + 16] = f2bf(c1[0] * d0); hb[1 * CH + 16] = f2bf(c1[1] * d1);
  hb[2 * CH + 16] = f2bf(c1[2] * d2); hb[3 * CH + 16] = f2bf(c1[3] * d3);
  hb[0 * CH + 32] = f2bf(c2[0] * d0); hb[1 * CH + 32] = f2bf(c2[1] * d1);
  hb[2 * CH + 32] = f2bf(c2[2] * d2); hb[3 * CH + 32] = f2bf(c2[3] * d3);
  hb[0 * CH + 48] = f2bf(c3[0] * d0); hb[1 * CH + 48] = f2bf(c3[1] * d1);
  hb[2 * CH + 48] = f2bf(c3[2] * d2); hb[3 * CH + 48] = f2bf(c3[3] * d3);
}

// -- layer-1 agg: FOUR nodes per wave (32 gathers in flight); bf16 out ---------
static __global__ __launch_bounds__(256) void k_agg64(const ushortT* __restrict__ h,
                                                      const float* __restrict__ dinv,
                                                      const int* __restrict__ rowstart,
                                                      const int* __restrict__ degi,
                                                      const int* __restrict__ csr_src,
                                                      const float* __restrict__ b1,
                                                      ushortT* __restrict__ aggb) {
  int wave = threadIdx.x >> 6, lane = threadIdx.x & 63;
  int i0n = __builtin_amdgcn_readfirstlane(blockIdx.x * 16 + wave * 4);
  float bias = b1[lane];
  float acc0 = bf2f(h[(size_t)(i0n + 0) * CH + lane]);
  float acc1 = bf2f(h[(size_t)(i0n + 1) * CH + lane]);
  float acc2 = bf2f(h[(size_t)(i0n + 2) * CH + lane]);
  float acc3 = bf2f(h[(size_t)(i0n + 3) * CH + lane]);
  int s0 = rowstart[i0n + 0], n0 = degi[i0n + 0];
  int s1 = rowstart[i0n + 1], n1 = degi[i0n + 1];
  int s2 = rowstart[i0n + 2], n2 = degi[i0n + 2];
  int s3 = rowstart[i0n + 3], n3 = degi[i0n + 3];
  int nmax = max(max(n0, n1), max(n2, n3));
  for (int it = 0; it < nmax; ++it) {
    int b0 = s0 + (n0 ? min(it, n0 - 1) : 0) * 8;
    int b1x = s1 + (n1 ? min(it, n1 - 1) : 0) * 8;
    int b2 = s2 + (n2 ? min(it, n2 - 1) : 0) * 8;
    int b3 = s3 + (n3 ? min(it, n3 - 1) : 0) * 8;
    float m0 = it < n0 ? 1.0f : 0.0f;
    float m1 = it < n1 ? 1.0f : 0.0f;
    float m2 = it < n2 ? 1.0f : 0.0f;
    float m3 = it < n3 ? 1.0f : 0.0f;
    float t0 = 0.f, t1 = 0.f, t2 = 0.f, t3 = 0.f;
#pragma unroll
    for (int q = 0; q < 8; ++q) {
      int ia = csr_src[b0 + q];
      int ib = csr_src[b1x + q];
      int ic = csr_src[b2 + q];
      int id = csr_src[b3 + q];
      t0 += bf2f(h[(size_t)ia * CH + lane]);
      t1 += bf2f(h[(size_t)ib * CH + lane]);
      t2 += bf2f(h[(size_t)ic * CH + lane]);
      t3 += bf2f(h[(size_t)id * CH + lane]);
    }
    acc0 += m0 * t0;
    acc1 += m1 * t1;
    acc2 += m2 * t2;
    acc3 += m3 * t3;
  }
  float v0 = acc0 * dinv[i0n + 0] + bias;
  float v1 = acc1 * dinv[i0n + 1] + bias;
  float v2 = acc2 * dinv[i0n + 2] + bias;
  float v3 = acc3 * dinv[i0n + 3] + bias;
  aggb[(size_t)(i0n + 0) * CH + lane] = f2bf(v0 > 0.0f ? v0 : 0.0f);
  aggb[(size_t)(i0n + 1) * CH + lane] = f2bf(v1 > 0.0f ? v1 : 0.0f);
  aggb[(size_t)(i0n + 2) * CH + lane] = f2bf(v2 > 0.0f ? v2 : 0.0f);
  aggb[(size_t)(i0n + 3) * CH + lane] = f2bf(v3 > 0.0f ? v3 : 0.0f);
}

// -- GEMM 2 (MFMA): h2 = bf16(dinv * (aggRelu @ W2)) ---------------------------
static __global__ __launch_bounds__(256) void k_gemm2(const ushortT* __restrict__ aggb,
                                                      const ushortT* __restrict__ W2T,
                                                      const float* __restrict__ dinv,
                                                      ushortT* __restrict__ h2) {
  if (blockIdx.x == 0 && threadIdx.x < CO) h2[(size_t)NN * CO + threadIdx.x] = 0;  // h2 sentinel
  int wave = threadIdx.x >> 6, lane = threadIdx.x & 63;
  int tile = blockIdx.x * 4 + wave;
  if (tile >= NTILE) return;
  int m = lane & 15;
  int kb = (lane >> 4) * 8;
  int row = tile * 16 + m;
  bfrag A0 = *(const bfrag*)(aggb + (size_t)row * CH + kb);
  bfrag A1 = *(const bfrag*)(aggb + (size_t)row * CH + kb + 32);
  int nl = lane & 15;
  ffrag z = {0.f, 0.f, 0.f, 0.f};
  bfrag B00 = *(const bfrag*)(W2T + (0 * 16 + nl) * CH + kb);
  bfrag B01 = *(const bfrag*)(W2T + (0 * 16 + nl) * CH + kb + 32);
  bfrag B10 = *(const bfrag*)(W2T + (1 * 16 + nl) * CH + kb);
  bfrag B11 = *(const bfrag*)(W2T + (1 * 16 + nl) * CH + kb + 32);
  ffrag c0 = __builtin_amdgcn_mfma_f32_16x16x32_bf16(A0, B00, z, 0, 0, 0);
  c0 = __builtin_amdgcn_mfma_f32_16x16x32_bf16(A1, B01, c0, 0, 0, 0);
  ffrag c1 = __builtin_amdgcn_mfma_f32_16x16x32_bf16(A0, B10, z, 0, 0, 0);
  c1 = __builtin_amdgcn_mfma_f32_16x16x32_bf16(A1, B11, c1, 0, 0, 0);
  int rbase = tile * 16 + (lane >> 4) * 4;
  float d0 = dinv[rbase + 0], d1 = dinv[rbase + 1], d2 = dinv[rbase + 2], d3 = dinv[rbase + 3];
  ushortT* hb = h2 + (size_t)rbase * CO + nl;
  hb[0 * CO + 0]  = f2bf(c0[0] * d0); hb[1 * CO + 0]  = f2bf(c0[1] * d1);
  hb[2 * CO + 0]  = f2bf(c0[2] * d2); hb[3 * CO + 0]  = f2bf(c0[3] * d3);
  hb[0 * CO + 16] = f2bf(c1[0] * d0); hb[1 * CO + 16] = f2bf(c1[1] * d1);
  hb[2 * CO + 16] = f2bf(c1[2] * d2); hb[3 * CO + 16] = f2bf(c1[3] * d3);
}

// -- layer-2 agg: FOUR nodes per wave; parity split per node; mean-pool --------
static __global__ __launch_bounds__(256) void k_agg32pool(const ushortT* __restrict__ h2,
                                                          const float* __restrict__ dinv,
                                                          const int* __restrict__ rowstart,
                                                          const int* __restrict__ degi,
                                                          const int* __restrict__ csr_src,
                                                          const int* __restrict__ batch,
                                                          const float* __restrict__ b2,
                                                          float* __restrict__ sums) {
  __shared__ float vals[16][CO];
  __shared__ int gid[16];
  int wave = threadIdx.x >> 6, lane = threadIdx.x & 63;
  int g = lane >> 5;          // neighbor parity 0/1
  int j = lane & 31;          // channel
  int i0n = __builtin_amdgcn_readfirstlane(blockIdx.x * 16 + wave * 4);
  int s0 = rowstart[i0n + 0], n0 = degi[i0n + 0];
  int s1 = rowstart[i0n + 1], n1 = degi[i0n + 1];
  int s2 = rowstart[i0n + 2], n2 = degi[i0n + 2];
  int s3 = rowstart[i0n + 3], n3 = degi[i0n + 3];
  float acc0 = 0.f, acc1 = 0.f, acc2 = 0.f, acc3 = 0.f;
  int nmax = max(max(n0, n1), max(n2, n3));
  for (int it = 0; it < nmax; ++it) {
    int b0 = s0 + (n0 ? min(it, n0 - 1) : 0) * 8;
    int b1x = s1 + (n1 ? min(it, n1 - 1) : 0) * 8;
    int b2 = s2 + (n2 ? min(it, n2 - 1) : 0) * 8;
    int b3 = s3 + (n3 ? min(it, n3 - 1) : 0) * 8;
    float m0 = it < n0 ? 1.0f : 0.0f;
    float m1 = it < n1 ? 1.0f : 0.0f;
    float m2 = it < n2 ? 1.0f : 0.0f;
    float m3 = it < n3 ? 1.0f : 0.0f;
    float t0 = 0.f, t1 = 0.f, t2 = 0.f, t3 = 0.f;
#pragma unroll
    for (int q = 0; q < 4; ++q) {
      int ia = csr_src[b0 + q * 2 + g];
      int ib = csr_src[b1x + q * 2 + g];
      int ic = csr_src[b2 + q * 2 + g];
      int id = csr_src[b3 + q * 2 + g];
      t0 += bf2f(h2[(size_t)ia * CO + j]);
      t1 += bf2f(h2[(size_t)ib * CO + j]);
      t2 += bf2f(h2[(size_t)ic * CO + j]);
      t3 += bf2f(h2[(size_t)id * CO + j]);
    }
    acc0 += m0 * t0;
    acc1 += m1 * t1;
    acc2 += m2 * t2;
    acc3 += m3 * t3;
  }
  acc0 += __shfl_xor(acc0, 32);   // combine neighbor parities
  acc1 += __shfl_xor(acc1, 32);
  acc2 += __shfl_xor(acc2, 32);
  acc3 += __shfl_xor(acc3, 32);
  if (g == 0) {
    acc0 += bf2f(h2[(size_t)(i0n + 0) * CO + j]);  // self-loops
    acc1 += bf2f(h2[(size_t)(i0n + 1) * CO + j]);
    acc2 += bf2f(h2[(size_t)(i0n + 2) * CO + j]);
    acc3 += bf2f(h2[(size_t)(i0n + 3) * CO + j]);
    float bb = b2[j];
    vals[wave * 4 + 0][j] = acc0 * dinv[i0n + 0] + bb;
    vals[wave * 4 + 1][j] = acc1 * dinv[i0n + 1] + bb;
    vals[wave * 4 + 2][j] = acc2 * dinv[i0n + 2] + bb;
    vals[wave * 4 + 3][j] = acc3 * dinv[i0n + 3] + bb;
    if (j == 0) {
      gid[wave * 4 + 0] = batch[i0n + 0];
      gid[wave * 4 + 1] = batch[i0n + 1];
      gid[wave * 4 + 2] = batch[i0n + 2];
      gid[wave * 4 + 3] = batch[i0n + 3];
    }
  }
  __syncthreads();
  if (threadIdx.x < 32) {
    int ch = threadIdx.x;
    float run = vals[0][ch];
    int gg = gid[0];
    for (int s = 1; s < 16; ++s) {
      if (gid[s] == gg) run += vals[s][ch];
      else { atomicAdd(&sums[gg * CO + ch], run); gg = gid[s]; run = vals[s][ch]; }
    }
    atomicAdd(&sums[gg * CO + ch], run);
  }
}

static __global__ void k_final(const float* __restrict__ sums, const float* __restrict__ counts,
                               float* __restrict__ out) {
  int t = blockIdx.x * 256 + threadIdx.x;
  if (t >= NG * CO) return;
  out[t] = sums[t] / fmaxf(counts[t >> 5], 1.0f);
}

extern "C" void kernel_launch(void* const* d_in, const int* in_sizes, int n_in,
                              void* d_out, int out_size, void* d_ws, size_t ws_size,
                              hipStream_t stream) {
  const float* x   = (const float*)d_in[0];
  const int* ei    = (const int*)d_in[1];   // [2, NE]: src = ei, dst = ei+NE
  const int* batch = (const int*)d_in[2];
  const float* W1  = (const float*)d_in[3];
  const float* b1  = (const float*)d_in[4];
  const float* W2  = (const float*)d_in[5];
  const float* b2  = (const float*)d_in[6];
  float* out = (float*)d_out;

  const int* src = ei;
  const int* dst = ei + NE;

  char* base = (char*)d_ws;
  size_t off = 0;
  auto allocB = [&](size_t nbytes) {
    void* p = (void*)(base + off);
    off += ((nbytes + 255) / 256) * 256;
    return p;
  };
  int* degi      = (int*)allocB(NN * 4);
  int* rowstart  = (int*)allocB(NN * 4);
  float* dinv    = (float*)allocB(NN * 4);
  int* bcursor   = (int*)allocB(128 * 4);
  ushortT* W1T   = (ushortT*)allocB(CIN * CH * 2);
  ushortT* W2T   = (ushortT*)allocB(CH * CO * 2);
  int* csr_src   = (int*)allocB((size_t)NBUCK * CSLOT * 4);     // 9.6 MB (padded)
  ushortT* hbuf  = (ushortT*)allocB((size_t)(NN + 1) * CH * 2); // h1 bf16 (+zero row); h2 reuses
  ushortT* aggb  = (ushortT*)allocB((size_t)(NN + 1) * CH * 2); // pairs (6.4 MB) then agg1 bf16
  float* sums    = (float*)allocB(NG * CO * 4);
  float* counts  = (float*)allocB(NG * 4);
  unsigned int* pairs = (unsigned int*)aggb;  // dead once k_bucket finishes

  dim3 B(256);
  // CSR build (fixed-slot buckets, fused scan+scatter, padded rows)
  k_zero<<<dim3(16), B, 0, stream>>>(sums, bcursor, batch, counts, W1, W1T, W2, W2T, hbuf);
  k_part<<<dim3(NBLKP), B, 0, stream>>>(src, dst, bcursor, pairs);
  k_bucket<<<dim3(NBUCK), dim3(1024), 0, stream>>>(pairs, bcursor, rowstart, degi, dinv, csr_src);
  // layer 1
  k_gemm1<<<dim3(GB), B, 0, stream>>>(x, W1T, dinv, hbuf);
  k_agg64<<<dim3(NN / 16), B, 0, stream>>>(hbuf, dinv, rowstart, degi, csr_src, b1, aggb);
  // layer 2
  k_gemm2<<<dim3(GB), B, 0, stream>>>(aggb, W2T, dinv, hbuf);
  k_agg32pool<<<dim3(NN / 16), B, 0, stream>>>(hbuf, dinv, rowstart, degi, csr_src, batch, b2, sums);
  // finalize
  k_final<<<dim3(16), B, 0, stream>>>(sums, counts, out);
}

// Round 25
// 129.625 us; speedup vs baseline: 2.0392x; 1.0163x over previous
//
#include <hip/hip_runtime.h>

#define NN 100000
#define NE 1250000
#define CIN 64
#define CH 64
#define CO 32
#define NG 128
#define NBUCK 196                    // buckets of 512 nodes: dst>>9 in [0,195]
#define BSHIFT 9
#define EPB 2048                     // edges per partition block
#define NBLKP ((NE + EPB - 1) / EPB) // 611
#define PSLOT 8192                   // pairs slots per bucket (max count ~6.7K)
#define CSLOT 12288                  // csr slots per bucket (count + pad <= 10.4K)
#define NTILE (NN / 16)              // 6250 MFMA row-tiles
#define GB ((NTILE + 3) / 4)         // 1563 blocks, 4 waves each

typedef unsigned short ushortT;
typedef __attribute__((ext_vector_type(8))) short bfrag;   // 8 bf16 (4 VGPR)
typedef __attribute__((ext_vector_type(4))) float ffrag;   // 4 fp32 acc

static __device__ inline ushortT f2bf(float v) {
  unsigned int u = __float_as_uint(v);
  u += 0x7FFFu + ((u >> 16) & 1u);   // round-to-nearest-even
  return (ushortT)(u >> 16);
}
static __device__ inline float bf2f(ushortT s) {
  return __uint_as_float(((unsigned int)s) << 16);
}
static __device__ inline bfrag pack8(float4 lo, float4 hi) {
  bfrag r;
  r[0] = (short)f2bf(lo.x); r[1] = (short)f2bf(lo.y);
  r[2] = (short)f2bf(lo.z); r[3] = (short)f2bf(lo.w);
  r[4] = (short)f2bf(hi.x); r[5] = (short)f2bf(hi.y);
  r[6] = (short)f2bf(hi.z); r[7] = (short)f2bf(hi.w);
  return r;
}

// -- init: sums, bucket cursors, counts, bf16-transposed weights, h1 sentinel --
static __global__ void k_zero(float* __restrict__ sums, int* __restrict__ bcursor,
                              const int* __restrict__ batch, float* __restrict__ counts,
                              const float* __restrict__ W1, ushortT* __restrict__ W1T,
                              const float* __restrict__ W2, ushortT* __restrict__ W2T,
                              ushortT* __restrict__ h) {
  int i = blockIdx.x * 256 + threadIdx.x;  // grid 16*256 = 4096
  if (i < NG * CO) sums[i] = 0.0f;
  if (i < 256) bcursor[i] = i * PSLOT;
  if (i < CH) h[(size_t)NN * CH + i] = 0;                    // h1 sentinel row
  if (i < CIN * CH) W1T[i] = f2bf(W1[(i & 63) * CH + (i >> 6)]);   // W1T[n][k]
  if (i < CH * CO) W2T[i] = f2bf(W2[(i & 63) * CO + (i >> 6)]);    // W2T[n][k]
  if (blockIdx.x == 0 && threadIdx.x < NG) {
    int g = threadIdx.x;
    int lo = 0, hi = NN;
    while (lo < hi) { int m = (lo + hi) >> 1; if (batch[m] < g) lo = m + 1; else hi = m; }
    int lb = lo;
    lo = 0; hi = NN;
    while (lo < hi) { int m = (lo + hi) >> 1; if (batch[m] <= g) lo = m + 1; else hi = m; }
    counts[g] = (float)(lo - lb);
  }
}

// -- partition edges into fixed-slot bucket runs: pk = src | (d&511)<<17 -------
static __global__ __launch_bounds__(256) void k_part(const int* __restrict__ src,
                                                     const int* __restrict__ dst,
                                                     int* __restrict__ bcursor,
                                                     unsigned int* __restrict__ pairs) {
  __shared__ int lh[256], lbase[256], loff[256];
  if (threadIdx.x < 256) { lh[threadIdx.x] = 0; loff[threadIdx.x] = 0; }
  __syncthreads();
  int e0 = blockIdx.x * EPB, e1 = min(e0 + EPB, NE);
  for (int e = e0 + threadIdx.x; e < e1; e += 256)
    atomicAdd(&lh[dst[e] >> BSHIFT], 1);
  __syncthreads();
  {
    int v = lh[threadIdx.x];
    lbase[threadIdx.x] = v ? atomicAdd(&bcursor[threadIdx.x], v) : 0;
  }
  __syncthreads();
  for (int e = e0 + threadIdx.x; e < e1; e += 256) {
    int d = dst[e], b = d >> BSHIFT;
    int o = atomicAdd(&loff[b], 1);
    pairs[lbase[b] + o] = (unsigned int)src[e] | ((unsigned int)(d & 511) << 17);
  }
}

// -- fused per-bucket: degree hist -> in-LDS scan (pad to 8) -> CSR scatter ----
static __global__ __launch_bounds__(512) void k_bucket(const unsigned int* __restrict__ pairs,
                                                       const int* __restrict__ bcursor,
                                                       int* __restrict__ rowstart,
                                                       int* __restrict__ degi,
                                                       float* __restrict__ dinv,
                                                       int* __restrict__ csr_src) {
  __shared__ int lh[512];
  __shared__ int tmp[512];
  __shared__ int cur[512];
  int t = threadIdx.x;
  int b = blockIdx.x, nb = b << BSHIFT;
  lh[t] = 0;
  __syncthreads();
  int p0 = b * PSLOT, p1 = bcursor[b];
  for (int p = p0 + t; p < p1; p += 512)
    atomicAdd(&lh[pairs[p] >> 17], 1);
  __syncthreads();
  int node = nb + t;
  int raw = lh[t];
  int pd = (raw + 7) & ~7;          // pad to multiple of 8
  tmp[t] = pd;
  __syncthreads();
  for (int off = 1; off < 512; off <<= 1) {
    int add = (t >= off) ? tmp[t - off] : 0;
    __syncthreads();
    tmp[t] += add;
    __syncthreads();
  }
  int ex = tmp[t] - pd;             // exclusive padded prefix within bucket
  int rs = b * CSLOT + ex;          // fixed-slot padded base
  if (node < NN) {
    rowstart[node] = rs;
    degi[node] = pd >> 3;           // niter (groups of 8)
    dinv[node] = rsqrtf((float)raw + 1.0f);
  }
  cur[t] = rs;
  __syncthreads();
  for (int p = p0 + t; p < p1; p += 512) {
    unsigned int pk = pairs[p];
    int pos = atomicAdd(&cur[pk >> 17], 1);
    csr_src[pos] = (int)(pk & 0x1FFFFu);
  }
  __syncthreads();
  for (int q = raw; q < pd; ++q) csr_src[rs + q] = NN;  // sentinel fill
}

// -- GEMM 1 (MFMA): h = bf16(dinv * (x @ W1)), 16-row tile per wave ------------
static __global__ __launch_bounds__(256) void k_gemm1(const float* __restrict__ x,
                                                      const ushortT* __restrict__ W1T,
                                                      const float* __restrict__ dinv,
                                                      ushortT* __restrict__ h) {
  int wave = threadIdx.x >> 6, lane = threadIdx.x & 63;
  int tile = blockIdx.x * 4 + wave;
  if (tile >= NTILE) return;
  int m = lane & 15;
  int kb = (lane >> 4) * 8;
  int row = tile * 16 + m;
  const float* xr = x + (size_t)row * CIN;
  float4 a0l = *(const float4*)(xr + kb);
  float4 a0h = *(const float4*)(xr + kb + 4);
  float4 a1l = *(const float4*)(xr + kb + 32);
  float4 a1h = *(const float4*)(xr + kb + 36);
  bfrag A0 = pack8(a0l, a0h);
  bfrag A1 = pack8(a1l, a1h);
  int nl = lane & 15;
  ffrag z = {0.f, 0.f, 0.f, 0.f};
  bfrag B00 = *(const bfrag*)(W1T + (0 * 16 + nl) * CIN + kb);
  bfrag B01 = *(const bfrag*)(W1T + (0 * 16 + nl) * CIN + kb + 32);
  bfrag B10 = *(const bfrag*)(W1T + (1 * 16 + nl) * CIN + kb);
  bfrag B11 = *(const bfrag*)(W1T + (1 * 16 + nl) * CIN + kb + 32);
  bfrag B20 = *(const bfrag*)(W1T + (2 * 16 + nl) * CIN + kb);
  bfrag B21 = *(const bfrag*)(W1T + (2 * 16 + nl) * CIN + kb + 32);
  bfrag B30 = *(const bfrag*)(W1T + (3 * 16 + nl) * CIN + kb);
  bfrag B31 = *(const bfrag*)(W1T + (3 * 16 + nl) * CIN + kb + 32);
  ffrag c0 = __builtin_amdgcn_mfma_f32_16x16x32_bf16(A0, B00, z, 0, 0, 0);
  c0 = __builtin_amdgcn_mfma_f32_16x16x32_bf16(A1, B01, c0, 0, 0, 0);
  ffrag c1 = __builtin_amdgcn_mfma_f32_16x16x32_bf16(A0, B10, z, 0, 0, 0);
  c1 = __builtin_amdgcn_mfma_f32_16x16x32_bf16(A1, B11, c1, 0, 0, 0);
  ffrag c2 = __builtin_amdgcn_mfma_f32_16x16x32_bf16(A0, B20, z, 0, 0, 0);
  c2 = __builtin_amdgcn_mfma_f32_16x16x32_bf16(A1, B21, c2, 0, 0, 0);
  ffrag c3 = __builtin_amdgcn_mfma_f32_16x16x32_bf16(A0, B30, z, 0, 0, 0);
  c3 = __builtin_amdgcn_mfma_f32_16x16x32_bf16(A1, B31, c3, 0, 0, 0);
  int rbase = tile * 16 + (lane >> 4) * 4;
  float d0 = dinv[rbase + 0], d1 = dinv[rbase + 1], d2 = dinv[rbase + 2], d3 = dinv[rbase + 3];
  ushortT* hb = h + (size_t)rbase * CH + nl;
  hb[0 * CH + 0]  = f2bf(c0[0] * d0); hb[1 * CH + 0]  = f2bf(c0[1] * d1);
  hb[2 * CH + 0]  = f2bf(c0[2] * d2); hb[3 * CH + 0]  = f2bf(c0[3] * d3);
  hb[0 * CH + 16] = f2bf(c1[0] * d0); hb[1 * CH + 16] = f2bf(c1[1] * d1);
  hb[2 * CH + 16] = f2bf(c1[2] * d2); hb[3 * CH + 16] = f2bf(c1[3] * d3);
  hb[0 * CH + 32] = f2bf(c2[0] * d0); hb[1 * CH + 32] = f2bf(c2[1] * d1);
  hb[2 * CH + 32] = f2bf(c2[2] * d2); hb[3 * CH + 32] = f2bf(c2[3] * d3);
  hb[0 * CH + 48] = f2bf(c3[0] * d0); hb[1 * CH + 48] = f2bf(c3[1] * d1);
  hb[2 * CH + 48] = f2bf(c3[2] * d2); hb[3 * CH + 48] = f2bf(c3[3] * d3);
}

// -- layer-1 agg: FOUR nodes per wave (32 gathers in flight); bf16 out ---------
static __global__ __launch_bounds__(256) void k_agg64(const ushortT* __restrict__ h,
                                                      const float* __restrict__ dinv,
                                                      const int* __restrict__ rowstart,
                                                      const int* __restrict__ degi,
                                                      const int* __restrict__ csr_src,
                                                      const float* __restrict__ b1,
                                                      ushortT* __restrict__ aggb) {
  int wave = threadIdx.x >> 6, lane = threadIdx.x & 63;
  int i0n = __builtin_amdgcn_readfirstlane(blockIdx.x * 16 + wave * 4);
  float bias = b1[lane];
  float acc0 = bf2f(h[(size_t)(i0n + 0) * CH + lane]);
  float acc1 = bf2f(h[(size_t)(i0n + 1) * CH + lane]);
  float acc2 = bf2f(h[(size_t)(i0n + 2) * CH + lane]);
  float acc3 = bf2f(h[(size_t)(i0n + 3) * CH + lane]);
  int s0 = rowstart[i0n + 0], n0 = degi[i0n + 0];
  int s1 = rowstart[i0n + 1], n1 = degi[i0n + 1];
  int s2 = rowstart[i0n + 2], n2 = degi[i0n + 2];
  int s3 = rowstart[i0n + 3], n3 = degi[i0n + 3];
  int nmax = max(max(n0, n1), max(n2, n3));
  for (int it = 0; it < nmax; ++it) {
    int b0 = s0 + (n0 ? min(it, n0 - 1) : 0) * 8;
    int b1x = s1 + (n1 ? min(it, n1 - 1) : 0) * 8;
    int b2 = s2 + (n2 ? min(it, n2 - 1) : 0) * 8;
    int b3 = s3 + (n3 ? min(it, n3 - 1) : 0) * 8;
    float m0 = it < n0 ? 1.0f : 0.0f;
    float m1 = it < n1 ? 1.0f : 0.0f;
    float m2 = it < n2 ? 1.0f : 0.0f;
    float m3 = it < n3 ? 1.0f : 0.0f;
    float t0 = 0.f, t1 = 0.f, t2 = 0.f, t3 = 0.f;
#pragma unroll
    for (int q = 0; q < 8; ++q) {
      int ia = csr_src[b0 + q];
      int ib = csr_src[b1x + q];
      int ic = csr_src[b2 + q];
      int id = csr_src[b3 + q];
      t0 += bf2f(h[(size_t)ia * CH + lane]);
      t1 += bf2f(h[(size_t)ib * CH + lane]);
      t2 += bf2f(h[(size_t)ic * CH + lane]);
      t3 += bf2f(h[(size_t)id * CH + lane]);
    }
    acc0 += m0 * t0;
    acc1 += m1 * t1;
    acc2 += m2 * t2;
    acc3 += m3 * t3;
  }
  float v0 = acc0 * dinv[i0n + 0] + bias;
  float v1 = acc1 * dinv[i0n + 1] + bias;
  float v2 = acc2 * dinv[i0n + 2] + bias;
  float v3 = acc3 * dinv[i0n + 3] + bias;
  aggb[(size_t)(i0n + 0) * CH + lane] = f2bf(v0 > 0.0f ? v0 : 0.0f);
  aggb[(size_t)(i0n + 1) * CH + lane] = f2bf(v1 > 0.0f ? v1 : 0.0f);
  aggb[(size_t)(i0n + 2) * CH + lane] = f2bf(v2 > 0.0f ? v2 : 0.0f);
  aggb[(size_t)(i0n + 3) * CH + lane] = f2bf(v3 > 0.0f ? v3 : 0.0f);
}

// -- GEMM 2 (MFMA): h2 = bf16(dinv * (aggRelu @ W2)) ---------------------------
static __global__ __launch_bounds__(256) void k_gemm2(const ushortT* __restrict__ aggb,
                                                      const ushortT* __restrict__ W2T,
                                                      const float* __restrict__ dinv,
                                                      ushortT* __restrict__ h2) {
  if (blockIdx.x == 0 && threadIdx.x < CO) h2[(size_t)NN * CO + threadIdx.x] = 0;  // h2 sentinel
  int wave = threadIdx.x >> 6, lane = threadIdx.x & 63;
  int tile = blockIdx.x * 4 + wave;
  if (tile >= NTILE) return;
  int m = lane & 15;
  int kb = (lane >> 4) * 8;
  int row = tile * 16 + m;
  bfrag A0 = *(const bfrag*)(aggb + (size_t)row * CH + kb);
  bfrag A1 = *(const bfrag*)(aggb + (size_t)row * CH + kb + 32);
  int nl = lane & 15;
  ffrag z = {0.f, 0.f, 0.f, 0.f};
  bfrag B00 = *(const bfrag*)(W2T + (0 * 16 + nl) * CH + kb);
  bfrag B01 = *(const bfrag*)(W2T + (0 * 16 + nl) * CH + kb + 32);
  bfrag B10 = *(const bfrag*)(W2T + (1 * 16 + nl) * CH + kb);
  bfrag B11 = *(const bfrag*)(W2T + (1 * 16 + nl) * CH + kb + 32);
  ffrag c0 = __builtin_amdgcn_mfma_f32_16x16x32_bf16(A0, B00, z, 0, 0, 0);
  c0 = __builtin_amdgcn_mfma_f32_16x16x32_bf16(A1, B01, c0, 0, 0, 0);
  ffrag c1 = __builtin_amdgcn_mfma_f32_16x16x32_bf16(A0, B10, z, 0, 0, 0);
  c1 = __builtin_amdgcn_mfma_f32_16x16x32_bf16(A1, B11, c1, 0, 0, 0);
  int rbase = tile * 16 + (lane >> 4) * 4;
  float d0 = dinv[rbase + 0], d1 = dinv[rbase + 1], d2 = dinv[rbase + 2], d3 = dinv[rbase + 3];
  ushortT* hb = h2 + (size_t)rbase * CO + nl;
  hb[0 * CO + 0]  = f2bf(c0[0] * d0); hb[1 * CO + 0]  = f2bf(c0[1] * d1);
  hb[2 * CO + 0]  = f2bf(c0[2] * d2); hb[3 * CO + 0]  = f2bf(c0[3] * d3);
  hb[0 * CO + 16] = f2bf(c1[0] * d0); hb[1 * CO + 16] = f2bf(c1[1] * d1);
  hb[2 * CO + 16] = f2bf(c1[2] * d2); hb[3 * CO + 16] = f2bf(c1[3] * d3);
}

// -- layer-2 agg: FOUR nodes per wave; parity split per node; mean-pool --------
static __global__ __launch_bounds__(256) void k_agg32pool(const ushortT* __restrict__ h2,
                                                          const float* __restrict__ dinv,
                                                          const int* __restrict__ rowstart,
                                                          const int* __restrict__ degi,
                                                          const int* __restrict__ csr_src,
                                                          const int* __restrict__ batch,
                                                          const float* __restrict__ b2,
                                                          float* __restrict__ sums) {
  __shared__ float vals[16][CO];
  __shared__ int gid[16];
  int wave = threadIdx.x >> 6, lane = threadIdx.x & 63;
  int g = lane >> 5;          // neighbor parity 0/1
  int j = lane & 31;          // channel
  int i0n = __builtin_amdgcn_readfirstlane(blockIdx.x * 16 + wave * 4);
  int s0 = rowstart[i0n + 0], n0 = degi[i0n + 0];
  int s1 = rowstart[i0n + 1], n1 = degi[i0n + 1];
  int s2 = rowstart[i0n + 2], n2 = degi[i0n + 2];
  int s3 = rowstart[i0n + 3], n3 = degi[i0n + 3];
  float acc0 = 0.f, acc1 = 0.f, acc2 = 0.f, acc3 = 0.f;
  int nmax = max(max(n0, n1), max(n2, n3));
  for (int it = 0; it < nmax; ++it) {
    int b0 = s0 + (n0 ? min(it, n0 - 1) : 0) * 8;
    int b1x = s1 + (n1 ? min(it, n1 - 1) : 0) * 8;
    int b2 = s2 + (n2 ? min(it, n2 - 1) : 0) * 8;
    int b3 = s3 + (n3 ? min(it, n3 - 1) : 0) * 8;
    float m0 = it < n0 ? 1.0f : 0.0f;
    float m1 = it < n1 ? 1.0f : 0.0f;
    float m2 = it < n2 ? 1.0f : 0.0f;
    float m3 = it < n3 ? 1.0f : 0.0f;
    float t0 = 0.f, t1 = 0.f, t2 = 0.f, t3 = 0.f;
#pragma unroll
    for (int q = 0; q < 4; ++q) {
      int ia = csr_src[b0 + q * 2 + g];
      int ib = csr_src[b1x + q * 2 + g];
      int ic = csr_src[b2 + q * 2 + g];
      int id = csr_src[b3 + q * 2 + g];
      t0 += bf2f(h2[(size_t)ia * CO + j]);
      t1 += bf2f(h2[(size_t)ib * CO + j]);
      t2 += bf2f(h2[(size_t)ic * CO + j]);
      t3 += bf2f(h2[(size_t)id * CO + j]);
    }
    acc0 += m0 * t0;
    acc1 += m1 * t1;
    acc2 += m2 * t2;
    acc3 += m3 * t3;
  }
  acc0 += __shfl_xor(acc0, 32);   // combine neighbor parities
  acc1 += __shfl_xor(acc1, 32);
  acc2 += __shfl_xor(acc2, 32);
  acc3 += __shfl_xor(acc3, 32);
  if (g == 0) {
    acc0 += bf2f(h2[(size_t)(i0n + 0) * CO + j]);  // self-loops
    acc1 += bf2f(h2[(size_t)(i0n + 1) * CO + j]);
    acc2 += bf2f(h2[(size_t)(i0n + 2) * CO + j]);
    acc3 += bf2f(h2[(size_t)(i0n + 3) * CO + j]);
    float bb = b2[j];
    vals[wave * 4 + 0][j] = acc0 * dinv[i0n + 0] + bb;
    vals[wave * 4 + 1][j] = acc1 * dinv[i0n + 1] + bb;
    vals[wave * 4 + 2][j] = acc2 * dinv[i0n + 2] + bb;
    vals[wave * 4 + 3][j] = acc3 * dinv[i0n + 3] + bb;
    if (j == 0) {
      gid[wave * 4 + 0] = batch[i0n + 0];
      gid[wave * 4 + 1] = batch[i0n + 1];
      gid[wave * 4 + 2] = batch[i0n + 2];
      gid[wave * 4 + 3] = batch[i0n + 3];
    }
  }
  __syncthreads();
  if (threadIdx.x < 32) {
    int ch = threadIdx.x;
    float run = vals[0][ch];
    int gg = gid[0];
    for (int s = 1; s < 16; ++s) {
      if (gid[s] == gg) run += vals[s][ch];
      else { atomicAdd(&sums[gg * CO + ch], run); gg = gid[s]; run = vals[s][ch]; }
    }
    atomicAdd(&sums[gg * CO + ch], run);
  }
}

static __global__ void k_final(const float* __restrict__ sums, const float* __restrict__ counts,
                               float* __restrict__ out) {
  int t = blockIdx.x * 256 + threadIdx.x;
  if (t >= NG * CO) return;
  out[t] = sums[t] / fmaxf(counts[t >> 5], 1.0f);
}

extern "C" void kernel_launch(void* const* d_in, const int* in_sizes, int n_in,
                              void* d_out, int out_size, void* d_ws, size_t ws_size,
                              hipStream_t stream) {
  const float* x   = (const float*)d_in[0];
  const int* ei    = (const int*)d_in[1];   // [2, NE]: src = ei, dst = ei+NE
  const int* batch = (const int*)d_in[2];
  const float* W1  = (const float*)d_in[3];
  const float* b1  = (const float*)d_in[4];
  const float* W2  = (const float*)d_in[5];
  const float* b2  = (const float*)d_in[6];
  float* out = (float*)d_out;

  const int* src = ei;
  const int* dst = ei + NE;

  char* base = (char*)d_ws;
  size_t off = 0;
  auto allocB = [&](size_t nbytes) {
    void* p = (void*)(base + off);
    off += ((nbytes + 255) / 256) * 256;
    return p;
  };
  int* degi      = (int*)allocB(NN * 4);
  int* rowstart  = (int*)allocB(NN * 4);
  float* dinv    = (float*)allocB(NN * 4);
  int* bcursor   = (int*)allocB(256 * 4);
  ushortT* W1T   = (ushortT*)allocB(CIN * CH * 2);
  ushortT* W2T   = (ushortT*)allocB(CH * CO * 2);
  int* csr_src   = (int*)allocB((size_t)NBUCK * CSLOT * 4);     // 9.6 MB (padded)
  ushortT* hbuf  = (ushortT*)allocB((size_t)(NN + 1) * CH * 2); // h1 bf16 (+zero row); h2 reuses
  ushortT* aggb  = (ushortT*)allocB((size_t)(NN + 1) * CH * 2); // pairs (6.4 MB) then agg1 bf16
  float* sums    = (float*)allocB(NG * CO * 4);
  float* counts  = (float*)allocB(NG * 4);
  unsigned int* pairs = (unsigned int*)aggb;  // dead once k_bucket finishes

  dim3 B(256);
  // CSR build (fixed-slot 512-node buckets, fused scan+scatter, padded rows)
  k_zero<<<dim3(16), B, 0, stream>>>(sums, bcursor, batch, counts, W1, W1T, W2, W2T, hbuf);
  k_part<<<dim3(NBLKP), B, 0, stream>>>(src, dst, bcursor, pairs);
  k_bucket<<<dim3(NBUCK), dim3(512), 0, stream>>>(pairs, bcursor, rowstart, degi, dinv, csr_src);
  // layer 1
  k_gemm1<<<dim3(GB), B, 0, stream>>>(x, W1T, dinv, hbuf);
  k_agg64<<<dim3(NN / 16), B, 0, stream>>>(hbuf, dinv, rowstart, degi, csr_src, b1, aggb);
  // layer 2
  k_gemm2<<<dim3(GB), B, 0, stream>>>(aggb, W2T, dinv, hbuf);
  k_agg32pool<<<dim3(NN / 16), B, 0, stream>>>(hbuf, dinv, rowstart, degi, csr_src, batch, b2, sums);
  // finalize
  k_final<<<dim3(16), B, 0, stream>>>(sums, counts, out);
}